// Round 8
// baseline (649.918 us; speedup 1.0000x reference)
//
#include <hip/hip_runtime.h>
#include <cstdint>
#include <cstddef>

typedef __bf16 bf16;
typedef __bf16 bf16x4 __attribute__((ext_vector_type(4)));
typedef __bf16 bf16x8 __attribute__((ext_vector_type(8)));
typedef float f32x4 __attribute__((ext_vector_type(4)));
typedef float f32x16 __attribute__((ext_vector_type(16)));
typedef unsigned int uint2v __attribute__((ext_vector_type(2)));

#define SLD 40  // fallback GEMM LDS row stride (elements)

// ---------------------------------------------------------------------------
// permlane32_swap helpers (attn softmax cross-half exchange)
// ---------------------------------------------------------------------------
__device__ __forceinline__ void plswap(unsigned& a, unsigned& b) {
  uint2v r = __builtin_amdgcn_permlane32_swap(a, b, false, false);
  a = r[0];
  b = r[1];
}
__device__ __forceinline__ float xhalf_max(float x) {
  unsigned a = __float_as_uint(x), b = a;
  plswap(a, b);
  return fmaxf(__uint_as_float(a), __uint_as_float(b));
}
__device__ __forceinline__ float xhalf_sum(float x) {
  unsigned a = __float_as_uint(x), b = a;
  plswap(a, b);
  return __uint_as_float(a) + __uint_as_float(b);
}
__device__ __forceinline__ unsigned cvtpk(float lo, float hi) {
  unsigned r;
  asm("v_cvt_pk_bf16_f32 %0, %1, %2" : "=v"(r) : "v"(lo), "v"(hi));
  return r;
}
__device__ __forceinline__ float f3(float a, float b, float c) {
  return fmaxf(fmaxf(a, b), c);  // clang fuses to v_max3_f32
}

template <int G0>
__device__ __forceinline__ bf16x8 build_pfrag(const f32x16& X) {
  unsigned a0 = cvtpk(X[G0 * 4 + 0], X[G0 * 4 + 1]);
  unsigned b0 = cvtpk(X[G0 * 4 + 4], X[G0 * 4 + 5]);
  plswap(a0, b0);
  unsigned a1 = cvtpk(X[G0 * 4 + 2], X[G0 * 4 + 3]);
  unsigned b1 = cvtpk(X[G0 * 4 + 6], X[G0 * 4 + 7]);
  plswap(a1, b1);
  union {
    unsigned w[4];
    bf16x8 v;
  } u;
  u.w[0] = a0;
  u.w[1] = a1;
  u.w[2] = b0;
  u.w[3] = b1;
  return u.v;
}

// ---------------------------------------------------------------------------
// FAST PATH: f32->bf16 convert pass + global_load_lds GEMMs (core v3).
// ---------------------------------------------------------------------------
__device__ __forceinline__ void gload16(const bf16* g, bf16* l) {
  __builtin_amdgcn_global_load_lds(
      (const __attribute__((address_space(1))) void*)g,
      (__attribute__((address_space(3))) void*)l, 16, 0, 0);
}

// Convert tensors: y<3 -> X (1M f32), y in 3..5 -> Wq/Wk/Wv (8M), y==6 -> Wfc.
__global__ __launch_bounds__(256)
void cvt7(const float* __restrict__ x0, const float* __restrict__ x1,
          const float* __restrict__ x2, const float* __restrict__ w0,
          const float* __restrict__ w1, const float* __restrict__ w2,
          const float* __restrict__ w3, bf16* __restrict__ xo,
          bf16* __restrict__ wo, bf16* __restrict__ wfo) {
  const int y = blockIdx.y;
  const int i = (blockIdx.x * 256 + threadIdx.x) * 8;
  const float* s;
  bf16* d;
  int n;
  if (y < 3) {
    s = (y == 0) ? x0 : (y == 1) ? x1 : x2;
    d = xo + (size_t)y * 1048576;
    n = 1048576;
  } else if (y < 6) {
    const int z = y - 3;
    s = (z == 0) ? w0 : (z == 1) ? w1 : w2;
    d = wo + (size_t)z * 8388608;
    n = 8388608;
  } else {
    s = w3;
    d = wfo;
    n = 8388608;
  }
  if (i >= n) return;
  f32x4 a = *(const f32x4*)(s + i);
  f32x4 b = *(const f32x4*)(s + i + 4);
  bf16x8 v;
#pragma unroll
  for (int j = 0; j < 4; ++j) {
    v[j] = (bf16)a[j];
    v[j + 4] = (bf16)b[j];
  }
  *(bf16x8*)(d + i) = v;
}

__global__ __launch_bounds__(256)
void cvt1(const float* __restrict__ s, bf16* __restrict__ d, int n) {
  const int i = (blockIdx.x * 256 + threadIdx.x) * 8;
  if (i >= n) return;
  f32x4 a = *(const f32x4*)(s + i);
  f32x4 b = *(const f32x4*)(s + i + 4);
  bf16x8 v;
#pragma unroll
  for (int j = 0; j < 4; ++j) {
    v[j] = (bf16)a[j];
    v[j + 4] = (bf16)b[j];
  }
  *(bf16x8*)(d + i) = v;
}

// Pipelined K-loop: NT GEMM 128x128 tile, BK=32, global_load_lds staging into
// a 2-buffer LDS ring. One barrier per K-step; stage(t+1) prefetch after it.
__device__ __forceinline__ void gemm_core_pipe(const bf16* __restrict__ A,
                                               const bf16* __restrict__ B,
                                               bf16* As, bf16* Bs, int K,
                                               int kbeg, int kend, int tm,
                                               int tn, f32x4 (&acc)[4][4]) {
  const int tid = threadIdx.x;
  const int w = tid >> 6, l = tid & 63;
  const int l15 = l & 15, quad = l >> 4;
  const int wm = (w >> 1) << 6, wn = (w & 1) << 6;
  const int rsub = l >> 2, csub = (l & 3) * 8;
  const int nt = (kend - kbeg) >> 5;

  auto stage = [&](int t) {
    const int k0 = kbeg + (t << 5);
    const int buf = (t & 1) * 4096;
#pragma unroll
    for (int c2 = 0; c2 < 2; ++c2) {
      const int c = w * 2 + c2;
      gload16(A + (size_t)(tm + c * 16 + rsub) * K + k0 + csub,
              As + buf + c * 512);
      gload16(B + (size_t)(tn + c * 16 + rsub) * K + k0 + csub,
              Bs + buf + c * 512);
    }
  };

  stage(0);

  for (int t = 0; t < nt; ++t) {
    __syncthreads();               // drains vmcnt(0): stage(t) visible
    if (t + 1 < nt) stage(t + 1);  // prefetch; drained at NEXT barrier

    const int buf = (t & 1) * 4096;
    bf16x8 af[4], bfr[4];
#pragma unroll
    for (int i = 0; i < 4; ++i)
      af[i] = *(const bf16x8*)(As + buf + (wm + i * 16 + l15) * 32 + quad * 8);
#pragma unroll
    for (int j = 0; j < 4; ++j)
      bfr[j] = *(const bf16x8*)(Bs + buf + (wn + j * 16 + l15) * 32 + quad * 8);
#pragma unroll
    for (int i = 0; i < 4; ++i)
#pragma unroll
      for (int j = 0; j < 4; ++j)
        acc[i][j] = __builtin_amdgcn_mfma_f32_16x16x32_bf16(af[i], bfr[j],
                                                            acc[i][j], 0, 0, 0);
  }
}

// Fused QKV projection, bf16 inputs. Grid (512, 3); blockIdx.y = slice.
//   slice 0 (Q): [bh][t][d],   t  = s*8 + c   (osc = qsc)
//   slice 1 (K): [bh][k''][d], k'' = c*256+s  (permuted key order)
//   slice 2 (V): [bh][d][k'']  (V^T, permuted) -> bf16x4 vectorized stores
__global__ __launch_bounds__(256, 4)
void qkv_gemm_lds(const bf16* __restrict__ Xc, const bf16* __restrict__ Wc,
                  const float* __restrict__ Bq, const float* __restrict__ Bk,
                  const float* __restrict__ Bv, bf16* __restrict__ Qo,
                  bf16* __restrict__ Ko, bf16* __restrict__ Vo, float qsc) {
  __shared__ bf16 As[2 * 4096];
  __shared__ bf16 Bs[2 * 4096];
  const int slice = blockIdx.y;
  const bf16* A = Xc + (size_t)slice * 1048576;
  const bf16* B = Wc + (size_t)slice * 8388608;
  const float* bias = (slice == 0) ? Bq : (slice == 1) ? Bk : Bv;
  const int tm = (blockIdx.x >> 6) << 7;  // tiles_n = 64
  const int tn = (blockIdx.x & 63) << 7;

  f32x4 acc[4][4] = {};
  gemm_core_pipe(A, B, As, Bs, 1024, 0, 1024, tm, tn, acc);

  const int tid = threadIdx.x;
  const int w = tid >> 6, l = tid & 63;
  const int l15 = l & 15, quad = l >> 4;
  const int wm = (w >> 1) << 6, wn = (w & 1) << 6;

  if (slice == 2) {
#pragma unroll
    for (int i = 0; i < 4; ++i) {
#pragma unroll
      for (int j = 0; j < 4; ++j) {
        const int n = tn + wn + j * 16 + l15;
        const int d = n & 127, h = (n >> 7) & 7, c = n >> 10;
        const float bv = bias[n];
        const int m0 = tm + wm + i * 16 + quad * 4;
        const int b = m0 >> 8, s0 = m0 & 255;
        const size_t idx = ((size_t)((b * 8 + h) * 128 + d)) * 2048 + (c << 8) + s0;
        bf16x4 ov;
#pragma unroll
        for (int r = 0; r < 4; ++r) ov[r] = (bf16)(acc[i][j][r] + bv);
        *(bf16x4*)(Vo + idx) = ov;
      }
    }
  } else {
    bf16* O = slice ? Ko : Qo;
    const float osc = slice ? 1.0f : qsc;
#pragma unroll
    for (int i = 0; i < 4; ++i) {
#pragma unroll
      for (int j = 0; j < 4; ++j) {
        const int n = tn + wn + j * 16 + l15;
        const int d = n & 127, h = (n >> 7) & 7, c = n >> 10;
        const float bv = bias[n];
#pragma unroll
        for (int r = 0; r < 4; ++r) {
          const int m = tm + wm + i * 16 + quad * 4 + r;
          const int b = m >> 8, s = m & 255;
          const int row = slice ? ((c << 8) | s) : ((s << 3) | c);
          const size_t idx = ((size_t)(b * 8 + h) * 2048 + row) * 128 + d;
          O[idx] = (bf16)((acc[i][j][r] + bv) * osc);
        }
      }
    }
  }
}

// Output projection, split-K x8: A=O2[1024][8192], B=Wfcc[1024][8192] bf16.
// Grid (64, 8). f32 partials to Pk; splitk_reduce adds bias.
__global__ __launch_bounds__(256, 4)
void fc_gemm_lds(const bf16* __restrict__ A, const bf16* __restrict__ B,
                 float* __restrict__ C) {
  __shared__ bf16 As[2 * 4096];
  __shared__ bf16 Bs[2 * 4096];
  const int tm = (blockIdx.x >> 3) << 7;
  const int tn = (blockIdx.x & 7) << 7;
  const int kbeg = blockIdx.y << 10;

  f32x4 acc[4][4] = {};
  gemm_core_pipe(A, B, As, Bs, 8192, kbeg, kbeg + 1024, tm, tn, acc);

  const int tid = threadIdx.x;
  const int w = tid >> 6, l = tid & 63;
  const int l15 = l & 15, quad = l >> 4;
  const int wm = (w >> 1) << 6, wn = (w & 1) << 6;
  const size_t koff = (size_t)blockIdx.y * 1048576;
#pragma unroll
  for (int i = 0; i < 4; ++i) {
#pragma unroll
    for (int j = 0; j < 4; ++j) {
      const int n = tn + wn + j * 16 + l15;
#pragma unroll
      for (int r = 0; r < 4; ++r) {
        const int m = tm + wm + i * 16 + quad * 4 + r;
        C[koff + (size_t)m * 1024 + n] = acc[i][j][r];
      }
    }
  }
}

// Sum 8 split-K partials + bias -> f32 out.
__global__ __launch_bounds__(256)
void splitk_reduce(const float* __restrict__ P, const float* __restrict__ bias,
                   float* __restrict__ out) {
  const int i = (blockIdx.x * 256 + threadIdx.x) * 4;
  const int n = i & 1023;
  f32x4 s = *(const f32x4*)(bias + n);
#pragma unroll
  for (int kc = 0; kc < 8; ++kc)
    s += *(const f32x4*)(P + (size_t)kc * 1048576 + i);
  *(f32x4*)(out + i) = s;
}

// ---------------------------------------------------------------------------
// Split-KV flash attention (fast path). Grid 1024 = 4 blocks/CU (16 waves/CU,
// 2x the TLP of the 512-block version). Block = (bh, qc, kh): 4 waves x 32
// q-rows, keys kh*1024..+1024 (16 iters of 64). Single-buffered 32KB K/V LDS,
// 2 barriers/iter (round-3 verified pattern). Writes UNNORMALIZED O partial
// (bf16) + per-row (m, lsum) f32; attn_merge combines the two halves exactly.
// ---------------------------------------------------------------------------
__global__ __launch_bounds__(256, 3)
void attn_split(const bf16* __restrict__ Q, const bf16* __restrict__ Kc,
                const bf16* __restrict__ Vt, bf16* __restrict__ OP,
                float* __restrict__ ML) {
  __shared__ bf16x8 KsV[1024];  // 64 keys x 128 d  (16KB)
  __shared__ bf16x8 VsV[1024];  // 128 d  x 64 keys (16KB)
  char* KsB = (char*)KsV;
  char* VsB = (char*)VsV;

  const int tid = threadIdx.x;
  const int w = tid >> 6, l = tid & 63;
  const int l31 = l & 31, hi = l >> 5;
  // XCD-chunked swizzle over 1024 blocks: 128 consecutive wg per XCD
  // (= 4 full (b,h) groups incl. both kv-halves -> K/V L2 reuse).
  const int wg = ((blockIdx.x & 7) << 7) | (blockIdx.x >> 3);
  const int bh = wg >> 5;
  const int qc = (wg >> 1) & 15;
  const int kh = wg & 1;
  const int q0w = qc * 128 + w * 32;
  const size_t qkbase = (size_t)bh * 2048 * 128;
  const size_t vbase = (size_t)bh * 128 * 2048;
  const int kbeg = kh << 10;

  bf16x8 qf[8];
#pragma unroll
  for (int dc = 0; dc < 8; ++dc)
    qf[dc] = *(const bf16x8*)(Q + qkbase + (size_t)(q0w + l31) * 128 + dc * 16 + hi * 8);

  f32x16 oacc[4] = {};
  float m = -1e30f, lsum = 0.f;

  bf16x8 kreg[4], vreg[4];
  auto stage_load = [&](int kk) {
#pragma unroll
    for (int pc = 0; pc < 4; ++pc) {
      const int c = tid + pc * 256;
      kreg[pc] = *(const bf16x8*)(Kc + qkbase + (size_t)(kk + (c >> 4)) * 128 + (c & 15) * 8);
      vreg[pc] = *(const bf16x8*)(Vt + vbase + (size_t)(c >> 3) * 2048 + kk + (c & 7) * 8);
    }
  };
  auto stage_write = [&]() {
#pragma unroll
    for (int pc = 0; pc < 4; ++pc) {
      const int c = tid + pc * 256;
      const int kr = c >> 4, kcol = c & 15;
      *(bf16x8*)(KsB + ((kr * 256 + kcol * 16) ^ ((kr & 15) << 4))) = kreg[pc];
      const int vr = c >> 3, vcol = c & 7;
      *(bf16x8*)(VsB + ((vr * 128 + vcol * 16) ^ ((vr & 7) << 4))) = vreg[pc];
    }
  };

  stage_load(kbeg);
  stage_write();
  __syncthreads();

  for (int it = 0; it < 16; ++it) {
    if (it < 15) stage_load(kbeg + (it + 1) * 64);

    f32x16 sa = {}, sb = {};
    __builtin_amdgcn_s_setprio(1);
#pragma unroll
    for (int dc = 0; dc < 8; ++dc) {
      const int colb = dc * 32 + hi * 16;
      bf16x8 ka = *(const bf16x8*)(KsB + ((l31 * 256 + colb) ^ ((l31 & 15) << 4)));
      bf16x8 kb = *(const bf16x8*)(KsB + (((32 + l31) * 256 + colb) ^ ((l31 & 15) << 4)));
      sa = __builtin_amdgcn_mfma_f32_32x32x16_bf16(ka, qf[dc], sa, 0, 0, 0);
      sb = __builtin_amdgcn_mfma_f32_32x32x16_bf16(kb, qf[dc], sb, 0, 0, 0);
    }
    __builtin_amdgcn_s_setprio(0);

    float mt;
    {
      float p0 = f3(sa[0], sa[1], sa[2]);
      float p1 = f3(sa[3], sa[4], sa[5]);
      float p2 = f3(sa[6], sa[7], sa[8]);
      float p3 = f3(sa[9], sa[10], sa[11]);
      float p4 = f3(sa[12], sa[13], sa[14]);
      float q0 = f3(sb[0], sb[1], sb[2]);
      float q1 = f3(sb[3], sb[4], sb[5]);
      float q2 = f3(sb[6], sb[7], sb[8]);
      float q3 = f3(sb[9], sb[10], sb[11]);
      float q4 = f3(sb[12], sb[13], sb[14]);
      float u0 = f3(p0, p1, p2);
      float u1 = f3(p3, p4, sa[15]);
      float u2 = f3(q0, q1, q2);
      float u3 = f3(q3, q4, sb[15]);
      mt = fmaxf(fmaxf(u0, u1), fmaxf(u2, u3));
      mt = xhalf_max(mt);
    }
    if (!__all(mt - m <= 8.0f)) {  // defer-max (T13)
      const float mn = fmaxf(m, mt);
      const float al = __builtin_amdgcn_exp2f(m - mn);
      m = mn;
      lsum *= al;
#pragma unroll
      for (int dt = 0; dt < 4; ++dt)
#pragma unroll
        for (int i = 0; i < 16; ++i) oacc[dt][i] *= al;
    }
#pragma unroll
    for (int i = 0; i < 16; ++i) sa[i] = __builtin_amdgcn_exp2f(sa[i] - m);
#pragma unroll
    for (int i = 0; i < 16; ++i) sb[i] = __builtin_amdgcn_exp2f(sb[i] - m);
    float r0 = 0.f, r1 = 0.f, r2 = 0.f, r3 = 0.f;
#pragma unroll
    for (int i = 0; i < 4; ++i) {
      r0 += sa[i]; r1 += sa[4 + i]; r2 += sa[8 + i]; r3 += sa[12 + i];
    }
#pragma unroll
    for (int i = 0; i < 4; ++i) {
      r0 += sb[i]; r1 += sb[4 + i]; r2 += sb[8 + i]; r3 += sb[12 + i];
    }
    lsum += xhalf_sum((r0 + r1) + (r2 + r3));

    bf16x8 pf[4];
    pf[0] = build_pfrag<0>(sa);
    pf[1] = build_pfrag<2>(sa);
    pf[2] = build_pfrag<0>(sb);
    pf[3] = build_pfrag<2>(sb);

    __builtin_amdgcn_s_setprio(1);
#pragma unroll
    for (int dt = 0; dt < 4; ++dt) {
      const int d = dt * 32 + l31;
#pragma unroll
      for (int c = 0; c < 4; ++c) {
        bf16x8 vf = *(const bf16x8*)(VsB + ((d * 128 + c * 32 + hi * 16) ^ ((d & 7) << 4)));
        oacc[dt] = __builtin_amdgcn_mfma_f32_32x32x16_bf16(vf, pf[c], oacc[dt], 0, 0, 0);
      }
    }
    __builtin_amdgcn_s_setprio(0);

    __syncthreads();              // all reads of LDS(it) done
    if (it < 15) stage_write();   // overwrite with tile it+1
    __syncthreads();              // writes visible
  }

  // epilogue: unnormalized partial (relative to this half's m)
  const int tq = q0w + l31;
  const size_t prow = (size_t)bh * 2048 + tq;
  bf16* P = OP + (size_t)kh * 8388608 + prow * 128;
#pragma unroll
  for (int dt = 0; dt < 4; ++dt) {
#pragma unroll
    for (int g = 0; g < 4; ++g) {
      const int d = dt * 32 + 8 * g + 4 * hi;
      bf16x4 ov;
#pragma unroll
      for (int r = 0; r < 4; ++r) ov[r] = (bf16)oacc[dt][g * 4 + r];
      *(bf16x4*)(P + d) = ov;
    }
  }
  if (hi == 0) {
    float* mlp = ML + ((size_t)kh * 65536 + prow) * 2;
    mlp[0] = m;
    mlp[1] = lsum;
  }
}

// Merge the two kv-halves: out = (P0*w0 + P1*w1) / (l0*w0 + l1*w1),
// wk = exp2(mk - max(m0,m1)) — exact for any per-half reference mk.
// Scatters to x2 layout [b][s][f], f = (t&7)*1024 + h*128 + d. 8192 blocks.
__global__ __launch_bounds__(256)
void attn_merge(const bf16* __restrict__ OP, const float* __restrict__ ML,
                bf16* __restrict__ O2) {
  const int i = blockIdx.x * 256 + threadIdx.x;  // 2M quads
  const int row = i >> 5;                        // 65536 rows (bh*2048+t)
  const int dq = (i & 31) * 4;
  const float m0 = ML[(size_t)row * 2], l0 = ML[(size_t)row * 2 + 1];
  const float m1 = ML[(size_t)(65536 + row) * 2];
  const float l1 = ML[(size_t)(65536 + row) * 2 + 1];
  const float M = fmaxf(m0, m1);
  const float w0 = __builtin_amdgcn_exp2f(m0 - M);
  const float w1 = __builtin_amdgcn_exp2f(m1 - M);
  const float inv = 1.0f / (l0 * w0 + l1 * w1);
  bf16x4 p0 = *(const bf16x4*)(OP + (size_t)row * 128 + dq);
  bf16x4 p1 = *(const bf16x4*)(OP + 8388608 + (size_t)row * 128 + dq);
  const int bh = row >> 11, t = row & 2047;
  const int b = bh >> 3, h = bh & 7;
  const size_t obase =
      (size_t)(b * 256 + (t >> 3)) * 8192 + (t & 7) * 1024 + h * 128 + dq;
  bf16x4 ov;
#pragma unroll
  for (int r = 0; r < 4; ++r)
    ov[r] = (bf16)(((float)p0[r] * w0 + (float)p1[r] * w1) * inv);
  *(bf16x4*)(O2 + obase) = ov;
}

// ---------------------------------------------------------------------------
// Full-KV attention (fallback paths only) — round-7 verified kernel.
// ---------------------------------------------------------------------------
__global__ __launch_bounds__(256, 2)
void attn_kernel(const bf16* __restrict__ Q, const bf16* __restrict__ Kc,
                 const bf16* __restrict__ Vt, bf16* __restrict__ O2) {
  __shared__ bf16x8 KsV[2048];
  __shared__ bf16x8 VsV[2048];
  char* KsB = (char*)KsV;
  char* VsB = (char*)VsV;

  const int tid = threadIdx.x;
  const int w = tid >> 6, l = tid & 63;
  const int l31 = l & 31, hi = l >> 5;
  const int wg = ((blockIdx.x & 7) << 6) | (blockIdx.x >> 3);
  const int bh = wg >> 4;
  const int qc = wg & 15;
  const int b = bh >> 3, h = bh & 7;
  const int q0w = qc * 128 + w * 32;
  const size_t qkbase = (size_t)bh * 2048 * 128;
  const size_t vbase = (size_t)bh * 128 * 2048;

  bf16x8 qf[8];
#pragma unroll
  for (int dc = 0; dc < 8; ++dc)
    qf[dc] = *(const bf16x8*)(Q + qkbase + (size_t)(q0w + l31) * 128 + dc * 16 + hi * 8);

  f32x16 oacc[4] = {};
  float m = -1e30f, lsum = 0.f;

  bf16x8 kreg[4], vreg[4];
  auto stage_load = [&](int kk) {
#pragma unroll
    for (int pc = 0; pc < 4; ++pc) {
      const int c = tid + pc * 256;
      kreg[pc] = *(const bf16x8*)(Kc + qkbase + (size_t)(kk + (c >> 4)) * 128 + (c & 15) * 8);
      vreg[pc] = *(const bf16x8*)(Vt + vbase + (size_t)(c >> 3) * 2048 + kk + (c & 7) * 8);
    }
  };
  auto stage_write = [&](int buf) {
    const int off = buf << 14;
#pragma unroll
    for (int pc = 0; pc < 4; ++pc) {
      const int c = tid + pc * 256;
      const int kr = c >> 4, kcol = c & 15;
      *(bf16x8*)(KsB + off + ((kr * 256 + kcol * 16) ^ ((kr & 15) << 4))) = kreg[pc];
      const int vr = c >> 3, vcol = c & 7;
      *(bf16x8*)(VsB + off + ((vr * 128 + vcol * 16) ^ ((vr & 7) << 4))) = vreg[pc];
    }
  };

  stage_load(0);
  stage_write(0);
  __syncthreads();
  int cur = 0;

  for (int it = 0; it < 32; ++it) {
    if (it < 31) stage_load((it + 1) * 64);
    const int koff = cur << 14;

    f32x16 sa = {}, sb = {};
    __builtin_amdgcn_s_setprio(1);
#pragma unroll
    for (int dc = 0; dc < 8; ++dc) {
      const int colb = dc * 32 + hi * 16;
      bf16x8 ka = *(const bf16x8*)(KsB + koff + ((l31 * 256 + colb) ^ ((l31 & 15) << 4)));
      bf16x8 kb = *(const bf16x8*)(KsB + koff + (((32 + l31) * 256 + colb) ^ ((l31 & 15) << 4)));
      sa = __builtin_amdgcn_mfma_f32_32x32x16_bf16(ka, qf[dc], sa, 0, 0, 0);
      sb = __builtin_amdgcn_mfma_f32_32x32x16_bf16(kb, qf[dc], sb, 0, 0, 0);
    }
    __builtin_amdgcn_s_setprio(0);

    float mt;
    {
      float p0 = f3(sa[0], sa[1], sa[2]);
      float p1 = f3(sa[3], sa[4], sa[5]);
      float p2 = f3(sa[6], sa[7], sa[8]);
      float p3 = f3(sa[9], sa[10], sa[11]);
      float p4 = f3(sa[12], sa[13], sa[14]);
      float q0 = f3(sb[0], sb[1], sb[2]);
      float q1 = f3(sb[3], sb[4], sb[5]);
      float q2 = f3(sb[6], sb[7], sb[8]);
      float q3 = f3(sb[9], sb[10], sb[11]);
      float q4 = f3(sb[12], sb[13], sb[14]);
      float u0 = f3(p0, p1, p2);
      float u1 = f3(p3, p4, sa[15]);
      float u2 = f3(q0, q1, q2);
      float u3 = f3(q3, q4, sb[15]);
      mt = fmaxf(fmaxf(u0, u1), fmaxf(u2, u3));
      mt = xhalf_max(mt);
    }
    if (!__all(mt - m <= 8.0f)) {
      const float mn = fmaxf(m, mt);
      const float al = __builtin_amdgcn_exp2f(m - mn);
      m = mn;
      lsum *= al;
#pragma unroll
      for (int dt = 0; dt < 4; ++dt)
#pragma unroll
        for (int i = 0; i < 16; ++i) oacc[dt][i] *= al;
    }
#pragma unroll
    for (int i = 0; i < 16; ++i) sa[i] = __builtin_amdgcn_exp2f(sa[i] - m);
#pragma unroll
    for (int i = 0; i < 16; ++i) sb[i] = __builtin_amdgcn_exp2f(sb[i] - m);
    float r0 = 0.f, r1 = 0.f, r2 = 0.f, r3 = 0.f;
#pragma unroll
    for (int i = 0; i < 4; ++i) {
      r0 += sa[i]; r1 += sa[4 + i]; r2 += sa[8 + i]; r3 += sa[12 + i];
    }
#pragma unroll
    for (int i = 0; i < 4; ++i) {
      r0 += sb[i]; r1 += sb[4 + i]; r2 += sb[8 + i]; r3 += sb[12 + i];
    }
    lsum += xhalf_sum((r0 + r1) + (r2 + r3));

    bf16x8 pf[4];
    pf[0] = build_pfrag<0>(sa);
    pf[1] = build_pfrag<2>(sa);
    pf[2] = build_pfrag<0>(sb);
    pf[3] = build_pfrag<2>(sb);

    __builtin_amdgcn_s_setprio(1);
#pragma unroll
    for (int dt = 0; dt < 4; ++dt) {
      const int d = dt * 32 + l31;
#pragma unroll
      for (int c = 0; c < 4; ++c) {
        bf16x8 vf = *(const bf16x8*)(VsB + koff + ((d * 128 + c * 32 + hi * 16) ^ ((d & 7) << 4)));
        oacc[dt] = __builtin_amdgcn_mfma_f32_32x32x16_bf16(vf, pf[c], oacc[dt], 0, 0, 0);
      }
    }
    __builtin_amdgcn_s_setprio(0);

    if (it < 31) stage_write(cur ^ 1);
    __syncthreads();
    cur ^= 1;
  }

  const float inv = 1.0f / lsum;
  const int t = q0w + l31;
  const size_t obase = (size_t)(b * 256 + (t >> 3)) * 8192 + (t & 7) * 1024 + h * 128;
#pragma unroll
  for (int dt = 0; dt < 4; ++dt) {
#pragma unroll
    for (int g = 0; g < 4; ++g) {
      const int d = dt * 32 + 8 * g + 4 * hi;
      bf16x4 ov;
#pragma unroll
      for (int r = 0; r < 4; ++r) ov[r] = (bf16)(oacc[dt][g * 4 + r] * inv);
      *(bf16x4*)(O2 + obase + d) = ov;
    }
  }
}

// ---------------------------------------------------------------------------
// FALLBACK GEMMs (ws < 120MB), verified earlier.
// ---------------------------------------------------------------------------
__global__ __launch_bounds__(256, 4)
void qkv_proj(const float* __restrict__ Xq, const float* __restrict__ Xk,
              const float* __restrict__ Xv, const float* __restrict__ Wq,
              const float* __restrict__ Wk, const float* __restrict__ Wv,
              const float* __restrict__ Bq, const float* __restrict__ Bk,
              const float* __restrict__ Bv, bf16* __restrict__ Qo,
              bf16* __restrict__ Ko, bf16* __restrict__ Vo, float qsc) {
  __shared__ bf16 As[128 * SLD];
  __shared__ bf16 Bs[128 * SLD];
  const int slice = blockIdx.y;
  const float* A = (slice == 0) ? Xq : (slice == 1) ? Xk : Xv;
  const float* W = (slice == 0) ? Wq : (slice == 1) ? Wk : Wv;
  const float* bias = (slice == 0) ? Bq : (slice == 1) ? Bk : Bv;

  const int tid = threadIdx.x;
  const int w = tid >> 6, l = tid & 63;
  const int l15 = l & 15, quad = l >> 4;
  const int tm = (blockIdx.x >> 6) << 7;
  const int tn = (blockIdx.x & 63) << 7;
  const int wm = (w >> 1) << 6;
  const int wn = (w & 1) << 6;

  const int frow = tid >> 1;
  const int fch = (tid & 1) * 16;

  f32x4 acc[4][4] = {};
  f32x4 ar[4], br[4];

  auto load_regs = [&](int k0) {
    const float* sA = A + (size_t)(tm + frow) * 1024 + k0 + fch;
    ar[0] = *(const f32x4*)(sA);
    ar[1] = *(const f32x4*)(sA + 4);
    ar[2] = *(const f32x4*)(sA + 8);
    ar[3] = *(const f32x4*)(sA + 12);
    const float* sB = W + (size_t)(tn + frow) * 1024 + k0 + fch;
    br[0] = *(const f32x4*)(sB);
    br[1] = *(const f32x4*)(sB + 4);
    br[2] = *(const f32x4*)(sB + 8);
    br[3] = *(const f32x4*)(sB + 12);
  };
  auto write_lds = [&]() {
    bf16x8 y0, y1;
#pragma unroll
    for (int j = 0; j < 4; ++j) {
      y0[j] = (bf16)ar[0][j]; y0[j + 4] = (bf16)ar[1][j];
      y1[j] = (bf16)ar[2][j]; y1[j + 4] = (bf16)ar[3][j];
    }
    *(bf16x8*)(As + frow * SLD + fch) = y0;
    *(bf16x8*)(As + frow * SLD + fch + 8) = y1;
#pragma unroll
    for (int j = 0; j < 4; ++j) {
      y0[j] = (bf16)br[0][j]; y0[j + 4] = (bf16)br[1][j];
      y1[j] = (bf16)br[2][j]; y1[j + 4] = (bf16)br[3][j];
    }
    *(bf16x8*)(Bs + frow * SLD + fch) = y0;
    *(bf16x8*)(Bs + frow * SLD + fch + 8) = y1;
  };

  load_regs(0);
  write_lds();
  __syncthreads();

  for (int k0 = 0; k0 < 1024; k0 += 32) {
    const bool more = (k0 + 32) < 1024;
    if (more) load_regs(k0 + 32);

    bf16x8 af[4], bfr[4];
#pragma unroll
    for (int i = 0; i < 4; ++i)
      af[i] = *(const bf16x8*)(As + (wm + i * 16 + l15) * SLD + quad * 8);
#pragma unroll
    for (int j = 0; j < 4; ++j)
      bfr[j] = *(const bf16x8*)(Bs + (wn + j * 16 + l15) * SLD + quad * 8);
#pragma unroll
    for (int i = 0; i < 4; ++i)
#pragma unroll
      for (int j = 0; j < 4; ++j)
        acc[i][j] = __builtin_amdgcn_mfma_f32_16x16x32_bf16(af[i], bfr[j], acc[i][j], 0, 0, 0);

    __syncthreads();
    if (more) {
      write_lds();
      __syncthreads();
    }
  }

  if (slice == 2) {
#pragma unroll
    for (int i = 0; i < 4; ++i) {
#pragma unroll
      for (int j = 0; j < 4; ++j) {
        const int n = tn + wn + j * 16 + l15;
        const int d = n & 127, h = (n >> 7) & 7, c = n >> 10;
        const float bv = bias[n];
        const int m0 = tm + wm + i * 16 + quad * 4;
        const int b = m0 >> 8, s0 = m0 & 255;
        const size_t idx = ((size_t)((b * 8 + h) * 128 + d)) * 2048 + (c << 8) + s0;
        bf16x4 ov;
#pragma unroll
        for (int r = 0; r < 4; ++r) ov[r] = (bf16)(acc[i][j][r] + bv);
        *(bf16x4*)(Vo + idx) = ov;
      }
    }
  } else {
    bf16* O = slice ? Ko : Qo;
    const float osc = slice ? 1.0f : qsc;
#pragma unroll
    for (int i = 0; i < 4; ++i) {
#pragma unroll
      for (int j = 0; j < 4; ++j) {
        const int n = tn + wn + j * 16 + l15;
        const int d = n & 127, h = (n >> 7) & 7, c = n >> 10;
        const float bv = bias[n];
#pragma unroll
        for (int r = 0; r < 4; ++r) {
          const int m = tm + wm + i * 16 + quad * 4 + r;
          const int b = m >> 8, s = m & 255;
          const int row = slice ? ((c << 8) | s) : ((s << 3) | c);
          const size_t idx = ((size_t)(b * 8 + h) * 2048 + row) * 128 + d;
          O[idx] = (bf16)((acc[i][j][r] + bv) * osc);
        }
      }
    }
  }
}

__global__ __launch_bounds__(256, 4)
void gemm_fc_f32(const bf16* __restrict__ Ap, const float* __restrict__ Bp,
                 float* __restrict__ C) {
  __shared__ bf16 As[128 * SLD];
  __shared__ bf16 Bs[128 * SLD];
  const int tid = threadIdx.x;
  const int w = tid >> 6, l = tid & 63;
  const int l15 = l & 15, quad = l >> 4;
  const int tm = (blockIdx.x >> 3) << 7;
  const int tn = (blockIdx.x & 7) << 7;
  const int wm = (w >> 1) << 6;
  const int wn = (w & 1) << 6;
  const int K = 8192;

  f32x4 acc[4][4] = {};
  const int frow = tid >> 1;
  const int fch = (tid & 1) * 16;
  const int kbeg = blockIdx.y << 10;
  const int kend = kbeg + 1024;

  f32x4 brf[4];
  bf16x8 arb[2];

  auto load_regs = [&](int k0) {
#pragma unroll
    for (int pc = 0; pc < 2; ++pc) {
      const int c = tid + pc * 256;
      const int r = c >> 2, col = (c & 3) * 8;
      arb[pc] = *(const bf16x8*)(Ap + (size_t)(tm + r) * K + k0 + col);
    }
    const float* src = Bp + (size_t)(tn + frow) * K + k0 + fch;
    brf[0] = *(const f32x4*)(src);
    brf[1] = *(const f32x4*)(src + 4);
    brf[2] = *(const f32x4*)(src + 8);
    brf[3] = *(const f32x4*)(src + 12);
  };
  auto write_lds = [&]() {
#pragma unroll
    for (int pc = 0; pc < 2; ++pc) {
      const int c = tid + pc * 256;
      const int r = c >> 2, col = (c & 3) * 8;
      *(bf16x8*)(As + r * SLD + col) = arb[pc];
    }
    bf16x8 y0, y1;
#pragma unroll
    for (int j = 0; j < 4; ++j) {
      y0[j] = (bf16)brf[0][j]; y0[j + 4] = (bf16)brf[1][j];
      y1[j] = (bf16)brf[2][j]; y1[j + 4] = (bf16)brf[3][j];
    }
    *(bf16x8*)(Bs + frow * SLD + fch) = y0;
    *(bf16x8*)(Bs + frow * SLD + fch + 8) = y1;
  };

  load_regs(kbeg);
  write_lds();
  __syncthreads();

  for (int k0 = kbeg; k0 < kend; k0 += 32) {
    const bool more = (k0 + 32) < kend;
    if (more) load_regs(k0 + 32);

    bf16x8 af[4], bfr[4];
#pragma unroll
    for (int i = 0; i < 4; ++i)
      af[i] = *(const bf16x8*)(As + (wm + i * 16 + l15) * SLD + quad * 8);
#pragma unroll
    for (int j = 0; j < 4; ++j)
      bfr[j] = *(const bf16x8*)(Bs + (wn + j * 16 + l15) * SLD + quad * 8);
#pragma unroll
    for (int i = 0; i < 4; ++i)
#pragma unroll
      for (int j = 0; j < 4; ++j)
        acc[i][j] = __builtin_amdgcn_mfma_f32_16x16x32_bf16(af[i], bfr[j], acc[i][j], 0, 0, 0);

    __syncthreads();
    if (more) {
      write_lds();
      __syncthreads();
    }
  }

  const size_t koff = (size_t)blockIdx.y * 1048576;
#pragma unroll
  for (int i = 0; i < 4; ++i) {
#pragma unroll
    for (int j = 0; j < 4; ++j) {
      const int n = tn + wn + j * 16 + l15;
#pragma unroll
      for (int r = 0; r < 4; ++r) {
        const int m = tm + wm + i * 16 + quad * 4 + r;
        C[koff + (size_t)m * 1024 + n] = acc[i][j][r];
      }
    }
  }
}

extern "C" void kernel_launch(void* const* d_in, const int* in_sizes, int n_in,
                              void* d_out, int out_size, void* d_ws, size_t ws_size,
                              hipStream_t stream) {
  const float* query = (const float*)d_in[0];
  const float* key_ = (const float*)d_in[1];
  const float* value = (const float*)d_in[2];
  const float* Wq = (const float*)d_in[3];
  const float* bq = (const float*)d_in[4];
  const float* Wk = (const float*)d_in[5];
  const float* bk = (const float*)d_in[6];
  const float* Wv = (const float*)d_in[7];
  const float* bv = (const float*)d_in[8];
  const float* Wfc = (const float*)d_in[9];
  const float* bfc = (const float*)d_in[10];
  float* out = (float*)d_out;  // output dtype FLOAT32

  const size_t MB = 1024 * 1024;
  bf16* Qws = (bf16*)d_ws;          // [0,16MB)
  bf16* Kws = Qws + 8 * MB;         // [16,32)
  bf16* Vtw = Kws + 8 * MB;         // [32,48)
  bf16* O2 = Vtw + 8 * MB;          // [48,64)
  float* Pk = (float*)((char*)d_ws + 16 * MB);  // [16,48) after attn

  const float QSC = 1.4426950408889634f / 32.0f;  // log2e / sqrt(HID)
  dim3 blk(256);

  if (ws_size >= (size_t)136 * MB) {
    // FAST PATH: convert all 7 tensors; split-KV attn; split-K fc.
    bf16* Xc = (bf16*)((char*)d_ws + 64 * MB);    // [64,70)
    bf16* Wc = (bf16*)((char*)d_ws + 70 * MB);    // [70,118) — dead after qkv
    bf16* Wfcc = (bf16*)((char*)d_ws + 118 * MB); // [118,134)
    bf16* OP = (bf16*)((char*)d_ws + 70 * MB);    // [70,102): 2 x 16MB partials
    float* ML = (float*)((char*)d_ws + 102 * MB); // [102,103): 2 x 512KB (m,l)

    cvt7<<<dim3(4096, 7), blk, 0, stream>>>(query, key_, value, Wq, Wk, Wv,
                                            Wfc, Xc, Wc, Wfcc);
    qkv_gemm_lds<<<dim3(512, 3), blk, 0, stream>>>(Xc, Wc, bq, bk, bv, Qws, Kws, Vtw, QSC);
    attn_split<<<1024, blk, 0, stream>>>(Qws, Kws, Vtw, OP, ML);
    attn_merge<<<8192, blk, 0, stream>>>(OP, ML, O2);
    fc_gemm_lds<<<dim3(64, 8), blk, 0, stream>>>(O2, Wfcc, Pk);
    splitk_reduce<<<1024, blk, 0, stream>>>(Pk, bfc, out);
  } else if (ws_size >= (size_t)120 * MB) {
    // FAST PATH, Wfc converted after attn into the dead Q region.
    bf16* Xc = (bf16*)((char*)d_ws + 64 * MB);
    bf16* Wc = (bf16*)((char*)d_ws + 70 * MB);
    bf16* Wfcc = Qws;  // reuse Qws after attn

    cvt7<<<dim3(4096, 6), blk, 0, stream>>>(query, key_, value, Wq, Wk, Wv,
                                            Wfc, Xc, Wc, nullptr);
    qkv_gemm_lds<<<dim3(512, 3), blk, 0, stream>>>(Xc, Wc, bq, bk, bv, Qws, Kws, Vtw, QSC);
    attn_kernel<<<512, blk, 0, stream>>>(Qws, Kws, Vtw, O2);
    cvt1<<<4096, blk, 0, stream>>>(Wfc, Wfcc, 8388608);
    fc_gemm_lds<<<dim3(64, 8), blk, 0, stream>>>(O2, Wfcc, Pk);
    splitk_reduce<<<1024, blk, 0, stream>>>(Pk, bfc, out);
  } else {
    // FALLBACK (fits in 64MB ws).
    qkv_proj<<<dim3(512, 3), blk, 0, stream>>>(query, key_, value, Wq, Wk, Wv,
                                               bq, bk, bv, Qws, Kws, Vtw, QSC);
    attn_kernel<<<512, blk, 0, stream>>>(Qws, Kws, Vtw, O2);
    gemm_fc_f32<<<dim3(64, 8), blk, 0, stream>>>(O2, Wfc, Pk);
    splitk_reduce<<<1024, blk, 0, stream>>>(Pk, bfc, out);
  }
}

// Round 9
// 386.261 us; speedup vs baseline: 1.6826x; 1.6826x over previous
//
#include <hip/hip_runtime.h>
#include <cstdint>
#include <cstddef>

typedef __bf16 bf16;
typedef __bf16 bf16x4 __attribute__((ext_vector_type(4)));
typedef __bf16 bf16x8 __attribute__((ext_vector_type(8)));
typedef float f32x4 __attribute__((ext_vector_type(4)));
typedef float f32x16 __attribute__((ext_vector_type(16)));
typedef unsigned int uint2v __attribute__((ext_vector_type(2)));

#define SLD 40  // fallback GEMM LDS row stride (elements)

// ---------------------------------------------------------------------------
// permlane32_swap helpers (attn softmax cross-half exchange)
// ---------------------------------------------------------------------------
__device__ __forceinline__ void plswap(unsigned& a, unsigned& b) {
  uint2v r = __builtin_amdgcn_permlane32_swap(a, b, false, false);
  a = r[0];
  b = r[1];
}
__device__ __forceinline__ float xhalf_max(float x) {
  unsigned a = __float_as_uint(x), b = a;
  plswap(a, b);
  return fmaxf(__uint_as_float(a), __uint_as_float(b));
}
__device__ __forceinline__ float xhalf_sum(float x) {
  unsigned a = __float_as_uint(x), b = a;
  plswap(a, b);
  return __uint_as_float(a) + __uint_as_float(b);
}
__device__ __forceinline__ unsigned cvtpk(float lo, float hi) {
  unsigned r;
  asm("v_cvt_pk_bf16_f32 %0, %1, %2" : "=v"(r) : "v"(lo), "v"(hi));
  return r;
}
__device__ __forceinline__ float f3(float a, float b, float c) {
  return fmaxf(fmaxf(a, b), c);  // clang fuses to v_max3_f32
}

template <int G0>
__device__ __forceinline__ bf16x8 build_pfrag(const f32x16& X) {
  unsigned a0 = cvtpk(X[G0 * 4 + 0], X[G0 * 4 + 1]);
  unsigned b0 = cvtpk(X[G0 * 4 + 4], X[G0 * 4 + 5]);
  plswap(a0, b0);
  unsigned a1 = cvtpk(X[G0 * 4 + 2], X[G0 * 4 + 3]);
  unsigned b1 = cvtpk(X[G0 * 4 + 6], X[G0 * 4 + 7]);
  plswap(a1, b1);
  union {
    unsigned w[4];
    bf16x8 v;
  } u;
  u.w[0] = a0;
  u.w[1] = a1;
  u.w[2] = b0;
  u.w[3] = b1;
  return u.v;
}

// ---------------------------------------------------------------------------
// FAST PATH: f32->bf16 convert pass + global_load_lds GEMMs (core v3).
// ---------------------------------------------------------------------------
__device__ __forceinline__ void gload16(const bf16* g, bf16* l) {
  __builtin_amdgcn_global_load_lds(
      (const __attribute__((address_space(1))) void*)g,
      (__attribute__((address_space(3))) void*)l, 16, 0, 0);
}

// Convert tensors: y<3 -> X (1M f32), y in 3..5 -> Wq/Wk/Wv (8M), y==6 -> Wfc.
__global__ __launch_bounds__(256)
void cvt7(const float* __restrict__ x0, const float* __restrict__ x1,
          const float* __restrict__ x2, const float* __restrict__ w0,
          const float* __restrict__ w1, const float* __restrict__ w2,
          const float* __restrict__ w3, bf16* __restrict__ xo,
          bf16* __restrict__ wo, bf16* __restrict__ wfo) {
  const int y = blockIdx.y;
  const int i = (blockIdx.x * 256 + threadIdx.x) * 8;
  const float* s;
  bf16* d;
  int n;
  if (y < 3) {
    s = (y == 0) ? x0 : (y == 1) ? x1 : x2;
    d = xo + (size_t)y * 1048576;
    n = 1048576;
  } else if (y < 6) {
    const int z = y - 3;
    s = (z == 0) ? w0 : (z == 1) ? w1 : w2;
    d = wo + (size_t)z * 8388608;
    n = 8388608;
  } else {
    s = w3;
    d = wfo;
    n = 8388608;
  }
  if (i >= n) return;
  f32x4 a = *(const f32x4*)(s + i);
  f32x4 b = *(const f32x4*)(s + i + 4);
  bf16x8 v;
#pragma unroll
  for (int j = 0; j < 4; ++j) {
    v[j] = (bf16)a[j];
    v[j + 4] = (bf16)b[j];
  }
  *(bf16x8*)(d + i) = v;
}

__global__ __launch_bounds__(256)
void cvt1(const float* __restrict__ s, bf16* __restrict__ d, int n) {
  const int i = (blockIdx.x * 256 + threadIdx.x) * 8;
  if (i >= n) return;
  f32x4 a = *(const f32x4*)(s + i);
  f32x4 b = *(const f32x4*)(s + i + 4);
  bf16x8 v;
#pragma unroll
  for (int j = 0; j < 4; ++j) {
    v[j] = (bf16)a[j];
    v[j + 4] = (bf16)b[j];
  }
  *(bf16x8*)(d + i) = v;
}

// Pipelined K-loop: NT GEMM 128x128 tile, BK=32, global_load_lds staging into
// a 2-buffer LDS ring. One barrier per K-step; stage(t+1) prefetch after it.
__device__ __forceinline__ void gemm_core_pipe(const bf16* __restrict__ A,
                                               const bf16* __restrict__ B,
                                               bf16* As, bf16* Bs, int K,
                                               int kbeg, int kend, int tm,
                                               int tn, f32x4 (&acc)[4][4]) {
  const int tid = threadIdx.x;
  const int w = tid >> 6, l = tid & 63;
  const int l15 = l & 15, quad = l >> 4;
  const int wm = (w >> 1) << 6, wn = (w & 1) << 6;
  const int rsub = l >> 2, csub = (l & 3) * 8;
  const int nt = (kend - kbeg) >> 5;

  auto stage = [&](int t) {
    const int k0 = kbeg + (t << 5);
    const int buf = (t & 1) * 4096;
#pragma unroll
    for (int c2 = 0; c2 < 2; ++c2) {
      const int c = w * 2 + c2;
      gload16(A + (size_t)(tm + c * 16 + rsub) * K + k0 + csub,
              As + buf + c * 512);
      gload16(B + (size_t)(tn + c * 16 + rsub) * K + k0 + csub,
              Bs + buf + c * 512);
    }
  };

  stage(0);

  for (int t = 0; t < nt; ++t) {
    __syncthreads();               // drains vmcnt(0): stage(t) visible
    if (t + 1 < nt) stage(t + 1);  // prefetch; drained at NEXT barrier

    const int buf = (t & 1) * 4096;
    bf16x8 af[4], bfr[4];
#pragma unroll
    for (int i = 0; i < 4; ++i)
      af[i] = *(const bf16x8*)(As + buf + (wm + i * 16 + l15) * 32 + quad * 8);
#pragma unroll
    for (int j = 0; j < 4; ++j)
      bfr[j] = *(const bf16x8*)(Bs + buf + (wn + j * 16 + l15) * 32 + quad * 8);
#pragma unroll
    for (int i = 0; i < 4; ++i)
#pragma unroll
      for (int j = 0; j < 4; ++j)
        acc[i][j] = __builtin_amdgcn_mfma_f32_16x16x32_bf16(af[i], bfr[j],
                                                            acc[i][j], 0, 0, 0);
  }
}

// Fused QKV projection, bf16 inputs. Grid (512, 3); blockIdx.y = slice.
//   slice 0 (Q): [bh][t][d],   t  = s*8 + c   (osc = qsc)
//   slice 1 (K): [bh][k''][d], k'' = c*256+s  (permuted key order)
//   slice 2 (V): [bh][d][k'']  (V^T, permuted) -> bf16x4 vectorized stores
// 32KB LDS -> 5 blocks/CU; VGPR budget 96 (measured ~88).
__global__ __launch_bounds__(256, 5)
void qkv_gemm_lds(const bf16* __restrict__ Xc, const bf16* __restrict__ Wc,
                  const float* __restrict__ Bq, const float* __restrict__ Bk,
                  const float* __restrict__ Bv, bf16* __restrict__ Qo,
                  bf16* __restrict__ Ko, bf16* __restrict__ Vo, float qsc) {
  __shared__ bf16 As[2 * 4096];
  __shared__ bf16 Bs[2 * 4096];
  const int slice = blockIdx.y;
  const bf16* A = Xc + (size_t)slice * 1048576;
  const bf16* B = Wc + (size_t)slice * 8388608;
  const float* bias = (slice == 0) ? Bq : (slice == 1) ? Bk : Bv;
  const int tm = (blockIdx.x >> 6) << 7;  // tiles_n = 64
  const int tn = (blockIdx.x & 63) << 7;

  f32x4 acc[4][4] = {};
  gemm_core_pipe(A, B, As, Bs, 1024, 0, 1024, tm, tn, acc);

  const int tid = threadIdx.x;
  const int w = tid >> 6, l = tid & 63;
  const int l15 = l & 15, quad = l >> 4;
  const int wm = (w >> 1) << 6, wn = (w & 1) << 6;

  if (slice == 2) {
#pragma unroll
    for (int i = 0; i < 4; ++i) {
#pragma unroll
      for (int j = 0; j < 4; ++j) {
        const int n = tn + wn + j * 16 + l15;
        const int d = n & 127, h = (n >> 7) & 7, c = n >> 10;
        const float bv = bias[n];
        const int m0 = tm + wm + i * 16 + quad * 4;
        const int b = m0 >> 8, s0 = m0 & 255;
        const size_t idx = ((size_t)((b * 8 + h) * 128 + d)) * 2048 + (c << 8) + s0;
        bf16x4 ov;
#pragma unroll
        for (int r = 0; r < 4; ++r) ov[r] = (bf16)(acc[i][j][r] + bv);
        *(bf16x4*)(Vo + idx) = ov;
      }
    }
  } else {
    bf16* O = slice ? Ko : Qo;
    const float osc = slice ? 1.0f : qsc;
#pragma unroll
    for (int i = 0; i < 4; ++i) {
#pragma unroll
      for (int j = 0; j < 4; ++j) {
        const int n = tn + wn + j * 16 + l15;
        const int d = n & 127, h = (n >> 7) & 7, c = n >> 10;
        const float bv = bias[n];
#pragma unroll
        for (int r = 0; r < 4; ++r) {
          const int m = tm + wm + i * 16 + quad * 4 + r;
          const int b = m >> 8, s = m & 255;
          const int row = slice ? ((c << 8) | s) : ((s << 3) | c);
          const size_t idx = ((size_t)(b * 8 + h) * 2048 + row) * 128 + d;
          O[idx] = (bf16)((acc[i][j][r] + bv) * osc);
        }
      }
    }
  }
}

// Output projection, split-K x8: A=O2[1024][8192], B=Wfcc[1024][8192] bf16.
// Grid (64, 8). f32 partials to Pk; splitk_reduce adds bias.
__global__ __launch_bounds__(256, 5)
void fc_gemm_lds(const bf16* __restrict__ A, const bf16* __restrict__ B,
                 float* __restrict__ C) {
  __shared__ bf16 As[2 * 4096];
  __shared__ bf16 Bs[2 * 4096];
  const int tm = (blockIdx.x >> 3) << 7;
  const int tn = (blockIdx.x & 7) << 7;
  const int kbeg = blockIdx.y << 10;

  f32x4 acc[4][4] = {};
  gemm_core_pipe(A, B, As, Bs, 8192, kbeg, kbeg + 1024, tm, tn, acc);

  const int tid = threadIdx.x;
  const int w = tid >> 6, l = tid & 63;
  const int l15 = l & 15, quad = l >> 4;
  const int wm = (w >> 1) << 6, wn = (w & 1) << 6;
  const size_t koff = (size_t)blockIdx.y * 1048576;
#pragma unroll
  for (int i = 0; i < 4; ++i) {
#pragma unroll
    for (int j = 0; j < 4; ++j) {
      const int n = tn + wn + j * 16 + l15;
#pragma unroll
      for (int r = 0; r < 4; ++r) {
        const int m = tm + wm + i * 16 + quad * 4 + r;
        C[koff + (size_t)m * 1024 + n] = acc[i][j][r];
      }
    }
  }
}

// Sum 8 split-K partials + bias -> f32 out.
__global__ __launch_bounds__(256)
void splitk_reduce(const float* __restrict__ P, const float* __restrict__ bias,
                   float* __restrict__ out) {
  const int i = (blockIdx.x * 256 + threadIdx.x) * 4;
  const int n = i & 1023;
  f32x4 s = *(const f32x4*)(bias + n);
#pragma unroll
  for (int kc = 0; kc < 8; ++kc)
    s += *(const f32x4*)(P + (size_t)kc * 1048576 + i);
  *(f32x4*)(out + i) = s;
}

// ---------------------------------------------------------------------------
// Flash attention, 32x32 swapped-operand, double-buffered K/V LDS (64KB),
// ONE barrier per K/V tile. Full KV per block (L2-reuse-protected: 16
// q-blocks per (b,h) share the 1MB K/V stream; FETCH ~25MB total).
// v_max3 max tree + VALU row-sum + defer-max.
// ---------------------------------------------------------------------------
__global__ __launch_bounds__(256, 2)
void attn_kernel(const bf16* __restrict__ Q, const bf16* __restrict__ Kc,
                 const bf16* __restrict__ Vt, bf16* __restrict__ O2) {
  __shared__ bf16x8 KsV[2048];  // 2 x (64 keys x 128 d)  (32KB)
  __shared__ bf16x8 VsV[2048];  // 2 x (128 d  x 64 keys) (32KB)
  char* KsB = (char*)KsV;
  char* VsB = (char*)VsV;

  const int tid = threadIdx.x;
  const int w = tid >> 6, l = tid & 63;
  const int l31 = l & 31, hi = l >> 5;
  const int wg = ((blockIdx.x & 7) << 6) | (blockIdx.x >> 3);
  const int bh = wg >> 4;
  const int qc = wg & 15;
  const int b = bh >> 3, h = bh & 7;
  const int q0w = qc * 128 + w * 32;
  const size_t qkbase = (size_t)bh * 2048 * 128;
  const size_t vbase = (size_t)bh * 128 * 2048;

  bf16x8 qf[8];
#pragma unroll
  for (int dc = 0; dc < 8; ++dc)
    qf[dc] = *(const bf16x8*)(Q + qkbase + (size_t)(q0w + l31) * 128 + dc * 16 + hi * 8);

  f32x16 oacc[4] = {};
  float m = -1e30f, lsum = 0.f;

  bf16x8 kreg[4], vreg[4];
  auto stage_load = [&](int kk) {
#pragma unroll
    for (int pc = 0; pc < 4; ++pc) {
      const int c = tid + pc * 256;
      kreg[pc] = *(const bf16x8*)(Kc + qkbase + (size_t)(kk + (c >> 4)) * 128 + (c & 15) * 8);
      vreg[pc] = *(const bf16x8*)(Vt + vbase + (size_t)(c >> 3) * 2048 + kk + (c & 7) * 8);
    }
  };
  auto stage_write = [&](int buf) {
    const int off = buf << 14;  // 16KB per buffer
#pragma unroll
    for (int pc = 0; pc < 4; ++pc) {
      const int c = tid + pc * 256;
      const int kr = c >> 4, kcol = c & 15;
      *(bf16x8*)(KsB + off + ((kr * 256 + kcol * 16) ^ ((kr & 15) << 4))) = kreg[pc];
      const int vr = c >> 3, vcol = c & 7;
      *(bf16x8*)(VsB + off + ((vr * 128 + vcol * 16) ^ ((vr & 7) << 4))) = vreg[pc];
    }
  };

  stage_load(0);
  stage_write(0);
  __syncthreads();
  int cur = 0;

  for (int it = 0; it < 32; ++it) {
    if (it < 31) stage_load((it + 1) * 64);
    const int koff = cur << 14;

    f32x16 sa = {}, sb = {};
    __builtin_amdgcn_s_setprio(1);
#pragma unroll
    for (int dc = 0; dc < 8; ++dc) {
      const int colb = dc * 32 + hi * 16;
      bf16x8 ka = *(const bf16x8*)(KsB + koff + ((l31 * 256 + colb) ^ ((l31 & 15) << 4)));
      bf16x8 kb = *(const bf16x8*)(KsB + koff + (((32 + l31) * 256 + colb) ^ ((l31 & 15) << 4)));
      sa = __builtin_amdgcn_mfma_f32_32x32x16_bf16(ka, qf[dc], sa, 0, 0, 0);
      sb = __builtin_amdgcn_mfma_f32_32x32x16_bf16(kb, qf[dc], sb, 0, 0, 0);
    }
    __builtin_amdgcn_s_setprio(0);

    float mt;
    {
      float p0 = f3(sa[0], sa[1], sa[2]);
      float p1 = f3(sa[3], sa[4], sa[5]);
      float p2 = f3(sa[6], sa[7], sa[8]);
      float p3 = f3(sa[9], sa[10], sa[11]);
      float p4 = f3(sa[12], sa[13], sa[14]);
      float q0 = f3(sb[0], sb[1], sb[2]);
      float q1 = f3(sb[3], sb[4], sb[5]);
      float q2 = f3(sb[6], sb[7], sb[8]);
      float q3 = f3(sb[9], sb[10], sb[11]);
      float q4 = f3(sb[12], sb[13], sb[14]);
      float u0 = f3(p0, p1, p2);
      float u1 = f3(p3, p4, sa[15]);
      float u2 = f3(q0, q1, q2);
      float u3 = f3(q3, q4, sb[15]);
      mt = fmaxf(fmaxf(u0, u1), fmaxf(u2, u3));
      mt = xhalf_max(mt);
    }
    if (!__all(mt - m <= 8.0f)) {  // defer-max (T13)
      const float mn = fmaxf(m, mt);
      const float al = __builtin_amdgcn_exp2f(m - mn);
      m = mn;
      lsum *= al;
#pragma unroll
      for (int dt = 0; dt < 4; ++dt)
#pragma unroll
        for (int i = 0; i < 16; ++i) oacc[dt][i] *= al;
    }
#pragma unroll
    for (int i = 0; i < 16; ++i) sa[i] = __builtin_amdgcn_exp2f(sa[i] - m);
#pragma unroll
    for (int i = 0; i < 16; ++i) sb[i] = __builtin_amdgcn_exp2f(sb[i] - m);
    float r0 = 0.f, r1 = 0.f, r2 = 0.f, r3 = 0.f;
#pragma unroll
    for (int i = 0; i < 4; ++i) {
      r0 += sa[i]; r1 += sa[4 + i]; r2 += sa[8 + i]; r3 += sa[12 + i];
    }
#pragma unroll
    for (int i = 0; i < 4; ++i) {
      r0 += sb[i]; r1 += sb[4 + i]; r2 += sb[8 + i]; r3 += sb[12 + i];
    }
    lsum += xhalf_sum((r0 + r1) + (r2 + r3));

    bf16x8 pf[4];
    pf[0] = build_pfrag<0>(sa);
    pf[1] = build_pfrag<2>(sa);
    pf[2] = build_pfrag<0>(sb);
    pf[3] = build_pfrag<2>(sb);

    __builtin_amdgcn_s_setprio(1);
#pragma unroll
    for (int dt = 0; dt < 4; ++dt) {
      const int d = dt * 32 + l31;
#pragma unroll
      for (int c = 0; c < 4; ++c) {
        bf16x8 vf = *(const bf16x8*)(VsB + koff + ((d * 128 + c * 32 + hi * 16) ^ ((d & 7) << 4)));
        oacc[dt] = __builtin_amdgcn_mfma_f32_32x32x16_bf16(vf, pf[c], oacc[dt], 0, 0, 0);
      }
    }
    __builtin_amdgcn_s_setprio(0);

    if (it < 31) stage_write(cur ^ 1);  // other buffer; safe post barrier(it-1)
    __syncthreads();                    // publish writes; reads of cur done
    cur ^= 1;
  }

  const float inv = 1.0f / lsum;
  const int t = q0w + l31;
  const size_t obase = (size_t)(b * 256 + (t >> 3)) * 8192 + (t & 7) * 1024 + h * 128;
#pragma unroll
  for (int dt = 0; dt < 4; ++dt) {
#pragma unroll
    for (int g = 0; g < 4; ++g) {
      const int d = dt * 32 + 8 * g + 4 * hi;
      bf16x4 ov;
#pragma unroll
      for (int r = 0; r < 4; ++r) ov[r] = (bf16)(oacc[dt][g * 4 + r] * inv);
      *(bf16x4*)(O2 + obase + d) = ov;
    }
  }
}

// ---------------------------------------------------------------------------
// FALLBACK GEMMs (ws < 120MB), verified earlier.
// ---------------------------------------------------------------------------
__global__ __launch_bounds__(256, 4)
void qkv_proj(const float* __restrict__ Xq, const float* __restrict__ Xk,
              const float* __restrict__ Xv, const float* __restrict__ Wq,
              const float* __restrict__ Wk, const float* __restrict__ Wv,
              const float* __restrict__ Bq, const float* __restrict__ Bk,
              const float* __restrict__ Bv, bf16* __restrict__ Qo,
              bf16* __restrict__ Ko, bf16* __restrict__ Vo, float qsc) {
  __shared__ bf16 As[128 * SLD];
  __shared__ bf16 Bs[128 * SLD];
  const int slice = blockIdx.y;
  const float* A = (slice == 0) ? Xq : (slice == 1) ? Xk : Xv;
  const float* W = (slice == 0) ? Wq : (slice == 1) ? Wk : Wv;
  const float* bias = (slice == 0) ? Bq : (slice == 1) ? Bk : Bv;

  const int tid = threadIdx.x;
  const int w = tid >> 6, l = tid & 63;
  const int l15 = l & 15, quad = l >> 4;
  const int tm = (blockIdx.x >> 6) << 7;
  const int tn = (blockIdx.x & 63) << 7;
  const int wm = (w >> 1) << 6;
  const int wn = (w & 1) << 6;

  const int frow = tid >> 1;
  const int fch = (tid & 1) * 16;

  f32x4 acc[4][4] = {};
  f32x4 ar[4], br[4];

  auto load_regs = [&](int k0) {
    const float* sA = A + (size_t)(tm + frow) * 1024 + k0 + fch;
    ar[0] = *(const f32x4*)(sA);
    ar[1] = *(const f32x4*)(sA + 4);
    ar[2] = *(const f32x4*)(sA + 8);
    ar[3] = *(const f32x4*)(sA + 12);
    const float* sB = W + (size_t)(tn + frow) * 1024 + k0 + fch;
    br[0] = *(const f32x4*)(sB);
    br[1] = *(const f32x4*)(sB + 4);
    br[2] = *(const f32x4*)(sB + 8);
    br[3] = *(const f32x4*)(sB + 12);
  };
  auto write_lds = [&]() {
    bf16x8 y0, y1;
#pragma unroll
    for (int j = 0; j < 4; ++j) {
      y0[j] = (bf16)ar[0][j]; y0[j + 4] = (bf16)ar[1][j];
      y1[j] = (bf16)ar[2][j]; y1[j + 4] = (bf16)ar[3][j];
    }
    *(bf16x8*)(As + frow * SLD + fch) = y0;
    *(bf16x8*)(As + frow * SLD + fch + 8) = y1;
#pragma unroll
    for (int j = 0; j < 4; ++j) {
      y0[j] = (bf16)br[0][j]; y0[j + 4] = (bf16)br[1][j];
      y1[j] = (bf16)br[2][j]; y1[j + 4] = (bf16)br[3][j];
    }
    *(bf16x8*)(Bs + frow * SLD + fch) = y0;
    *(bf16x8*)(Bs + frow * SLD + fch + 8) = y1;
  };

  load_regs(0);
  write_lds();
  __syncthreads();

  for (int k0 = 0; k0 < 1024; k0 += 32) {
    const bool more = (k0 + 32) < 1024;
    if (more) load_regs(k0 + 32);

    bf16x8 af[4], bfr[4];
#pragma unroll
    for (int i = 0; i < 4; ++i)
      af[i] = *(const bf16x8*)(As + (wm + i * 16 + l15) * SLD + quad * 8);
#pragma unroll
    for (int j = 0; j < 4; ++j)
      bfr[j] = *(const bf16x8*)(Bs + (wn + j * 16 + l15) * SLD + quad * 8);
#pragma unroll
    for (int i = 0; i < 4; ++i)
#pragma unroll
      for (int j = 0; j < 4; ++j)
        acc[i][j] = __builtin_amdgcn_mfma_f32_16x16x32_bf16(af[i], bfr[j], acc[i][j], 0, 0, 0);

    __syncthreads();
    if (more) {
      write_lds();
      __syncthreads();
    }
  }

  if (slice == 2) {
#pragma unroll
    for (int i = 0; i < 4; ++i) {
#pragma unroll
      for (int j = 0; j < 4; ++j) {
        const int n = tn + wn + j * 16 + l15;
        const int d = n & 127, h = (n >> 7) & 7, c = n >> 10;
        const float bv = bias[n];
        const int m0 = tm + wm + i * 16 + quad * 4;
        const int b = m0 >> 8, s0 = m0 & 255;
        const size_t idx = ((size_t)((b * 8 + h) * 128 + d)) * 2048 + (c << 8) + s0;
        bf16x4 ov;
#pragma unroll
        for (int r = 0; r < 4; ++r) ov[r] = (bf16)(acc[i][j][r] + bv);
        *(bf16x4*)(Vo + idx) = ov;
      }
    }
  } else {
    bf16* O = slice ? Ko : Qo;
    const float osc = slice ? 1.0f : qsc;
#pragma unroll
    for (int i = 0; i < 4; ++i) {
#pragma unroll
      for (int j = 0; j < 4; ++j) {
        const int n = tn + wn + j * 16 + l15;
        const int d = n & 127, h = (n >> 7) & 7, c = n >> 10;
        const float bv = bias[n];
#pragma unroll
        for (int r = 0; r < 4; ++r) {
          const int m = tm + wm + i * 16 + quad * 4 + r;
          const int b = m >> 8, s = m & 255;
          const int row = slice ? ((c << 8) | s) : ((s << 3) | c);
          const size_t idx = ((size_t)(b * 8 + h) * 2048 + row) * 128 + d;
          O[idx] = (bf16)((acc[i][j][r] + bv) * osc);
        }
      }
    }
  }
}

__global__ __launch_bounds__(256, 4)
void gemm_fc_f32(const bf16* __restrict__ Ap, const float* __restrict__ Bp,
                 float* __restrict__ C) {
  __shared__ bf16 As[128 * SLD];
  __shared__ bf16 Bs[128 * SLD];
  const int tid = threadIdx.x;
  const int w = tid >> 6, l = tid & 63;
  const int l15 = l & 15, quad = l >> 4;
  const int tm = (blockIdx.x >> 3) << 7;
  const int tn = (blockIdx.x & 7) << 7;
  const int wm = (w >> 1) << 6;
  const int wn = (w & 1) << 6;
  const int K = 8192;

  f32x4 acc[4][4] = {};
  const int frow = tid >> 1;
  const int fch = (tid & 1) * 16;
  const int kbeg = blockIdx.y << 10;
  const int kend = kbeg + 1024;

  f32x4 brf[4];
  bf16x8 arb[2];

  auto load_regs = [&](int k0) {
#pragma unroll
    for (int pc = 0; pc < 2; ++pc) {
      const int c = tid + pc * 256;
      const int r = c >> 2, col = (c & 3) * 8;
      arb[pc] = *(const bf16x8*)(Ap + (size_t)(tm + r) * K + k0 + col);
    }
    const float* src = Bp + (size_t)(tn + frow) * K + k0 + fch;
    brf[0] = *(const f32x4*)(src);
    brf[1] = *(const f32x4*)(src + 4);
    brf[2] = *(const f32x4*)(src + 8);
    brf[3] = *(const f32x4*)(src + 12);
  };
  auto write_lds = [&]() {
#pragma unroll
    for (int pc = 0; pc < 2; ++pc) {
      const int c = tid + pc * 256;
      const int r = c >> 2, col = (c & 3) * 8;
      *(bf16x8*)(As + r * SLD + col) = arb[pc];
    }
    bf16x8 y0, y1;
#pragma unroll
    for (int j = 0; j < 4; ++j) {
      y0[j] = (bf16)brf[0][j]; y0[j + 4] = (bf16)brf[1][j];
      y1[j] = (bf16)brf[2][j]; y1[j + 4] = (bf16)brf[3][j];
    }
    *(bf16x8*)(Bs + frow * SLD + fch) = y0;
    *(bf16x8*)(Bs + frow * SLD + fch + 8) = y1;
  };

  load_regs(kbeg);
  write_lds();
  __syncthreads();

  for (int k0 = kbeg; k0 < kend; k0 += 32) {
    const bool more = (k0 + 32) < kend;
    if (more) load_regs(k0 + 32);

    bf16x8 af[4], bfr[4];
#pragma unroll
    for (int i = 0; i < 4; ++i)
      af[i] = *(const bf16x8*)(As + (wm + i * 16 + l15) * SLD + quad * 8);
#pragma unroll
    for (int j = 0; j < 4; ++j)
      bfr[j] = *(const bf16x8*)(Bs + (wn + j * 16 + l15) * SLD + quad * 8);
#pragma unroll
    for (int i = 0; i < 4; ++i)
#pragma unroll
      for (int j = 0; j < 4; ++j)
        acc[i][j] = __builtin_amdgcn_mfma_f32_16x16x32_bf16(af[i], bfr[j], acc[i][j], 0, 0, 0);

    __syncthreads();
    if (more) {
      write_lds();
      __syncthreads();
    }
  }

  const size_t koff = (size_t)blockIdx.y * 1048576;
#pragma unroll
  for (int i = 0; i < 4; ++i) {
#pragma unroll
    for (int j = 0; j < 4; ++j) {
      const int n = tn + wn + j * 16 + l15;
#pragma unroll
      for (int r = 0; r < 4; ++r) {
        const int m = tm + wm + i * 16 + quad * 4 + r;
        C[koff + (size_t)m * 1024 + n] = acc[i][j][r];
      }
    }
  }
}

extern "C" void kernel_launch(void* const* d_in, const int* in_sizes, int n_in,
                              void* d_out, int out_size, void* d_ws, size_t ws_size,
                              hipStream_t stream) {
  const float* query = (const float*)d_in[0];
  const float* key_ = (const float*)d_in[1];
  const float* value = (const float*)d_in[2];
  const float* Wq = (const float*)d_in[3];
  const float* bq = (const float*)d_in[4];
  const float* Wk = (const float*)d_in[5];
  const float* bk = (const float*)d_in[6];
  const float* Wv = (const float*)d_in[7];
  const float* bv = (const float*)d_in[8];
  const float* Wfc = (const float*)d_in[9];
  const float* bfc = (const float*)d_in[10];
  float* out = (float*)d_out;  // output dtype FLOAT32

  const size_t MB = 1024 * 1024;
  bf16* Qws = (bf16*)d_ws;          // [0,16MB)
  bf16* Kws = Qws + 8 * MB;         // [16,32)
  bf16* Vtw = Kws + 8 * MB;         // [32,48)
  bf16* O2 = Vtw + 8 * MB;          // [48,64)
  float* Pk = (float*)((char*)d_ws + 16 * MB);  // [16,48) after attn

  const float QSC = 1.4426950408889634f / 32.0f;  // log2e / sqrt(HID)
  dim3 blk(256);

  if (ws_size >= (size_t)136 * MB) {
    // FAST PATH: convert all 7 tensors; full-KV attn; split-K fc.
    bf16* Xc = (bf16*)((char*)d_ws + 64 * MB);    // [64,70)
    bf16* Wc = (bf16*)((char*)d_ws + 70 * MB);    // [70,118)
    bf16* Wfcc = (bf16*)((char*)d_ws + 118 * MB); // [118,134)

    cvt7<<<dim3(4096, 7), blk, 0, stream>>>(query, key_, value, Wq, Wk, Wv,
                                            Wfc, Xc, Wc, Wfcc);
    qkv_gemm_lds<<<dim3(512, 3), blk, 0, stream>>>(Xc, Wc, bq, bk, bv, Qws, Kws, Vtw, QSC);
    attn_kernel<<<512, blk, 0, stream>>>(Qws, Kws, Vtw, O2);
    fc_gemm_lds<<<dim3(64, 8), blk, 0, stream>>>(O2, Wfcc, Pk);
    splitk_reduce<<<1024, blk, 0, stream>>>(Pk, bfc, out);
  } else if (ws_size >= (size_t)120 * MB) {
    // FAST PATH, Wfc converted after attn into the dead Q region.
    bf16* Xc = (bf16*)((char*)d_ws + 64 * MB);
    bf16* Wc = (bf16*)((char*)d_ws + 70 * MB);
    bf16* Wfcc = Qws;  // reuse Qws after attn

    cvt7<<<dim3(4096, 6), blk, 0, stream>>>(query, key_, value, Wq, Wk, Wv,
                                            Wfc, Xc, Wc, nullptr);
    qkv_gemm_lds<<<dim3(512, 3), blk, 0, stream>>>(Xc, Wc, bq, bk, bv, Qws, Kws, Vtw, QSC);
    attn_kernel<<<512, blk, 0, stream>>>(Qws, Kws, Vtw, O2);
    cvt1<<<4096, blk, 0, stream>>>(Wfc, Wfcc, 8388608);
    fc_gemm_lds<<<dim3(64, 8), blk, 0, stream>>>(O2, Wfcc, Pk);
    splitk_reduce<<<1024, blk, 0, stream>>>(Pk, bfc, out);
  } else {
    // FALLBACK (fits in 64MB ws).
    qkv_proj<<<dim3(512, 3), blk, 0, stream>>>(query, key_, value, Wq, Wk, Wv,
                                               bq, bk, bv, Qws, Kws, Vtw, QSC);
    attn_kernel<<<512, blk, 0, stream>>>(Qws, Kws, Vtw, O2);
    gemm_fc_f32<<<dim3(64, 8), blk, 0, stream>>>(O2, Wfc, Pk);
    splitk_reduce<<<1024, blk, 0, stream>>>(Pk, bfc, out);
  }
}

// Round 10
// 366.162 us; speedup vs baseline: 1.7749x; 1.0549x over previous
//
#include <hip/hip_runtime.h>
#include <cstdint>
#include <cstddef>

typedef __bf16 bf16;
typedef __bf16 bf16x4 __attribute__((ext_vector_type(4)));
typedef __bf16 bf16x8 __attribute__((ext_vector_type(8)));
typedef float f32x4 __attribute__((ext_vector_type(4)));
typedef float f32x16 __attribute__((ext_vector_type(16)));
typedef unsigned int uint2v __attribute__((ext_vector_type(2)));

#define SLD 40  // fallback GEMM LDS row stride (elements)

// ---------------------------------------------------------------------------
// permlane32_swap helpers (attn softmax cross-half exchange)
// ---------------------------------------------------------------------------
__device__ __forceinline__ void plswap(unsigned& a, unsigned& b) {
  uint2v r = __builtin_amdgcn_permlane32_swap(a, b, false, false);
  a = r[0];
  b = r[1];
}
__device__ __forceinline__ float xhalf_max(float x) {
  unsigned a = __float_as_uint(x), b = a;
  plswap(a, b);
  return fmaxf(__uint_as_float(a), __uint_as_float(b));
}
__device__ __forceinline__ float xhalf_sum(float x) {
  unsigned a = __float_as_uint(x), b = a;
  plswap(a, b);
  return __uint_as_float(a) + __uint_as_float(b);
}
__device__ __forceinline__ unsigned cvtpk(float lo, float hi) {
  unsigned r;
  asm("v_cvt_pk_bf16_f32 %0, %1, %2" : "=v"(r) : "v"(lo), "v"(hi));
  return r;
}
__device__ __forceinline__ float f3(float a, float b, float c) {
  return fmaxf(fmaxf(a, b), c);  // clang fuses to v_max3_f32
}

template <int G0>
__device__ __forceinline__ bf16x8 build_pfrag(const f32x16& X) {
  unsigned a0 = cvtpk(X[G0 * 4 + 0], X[G0 * 4 + 1]);
  unsigned b0 = cvtpk(X[G0 * 4 + 4], X[G0 * 4 + 5]);
  plswap(a0, b0);
  unsigned a1 = cvtpk(X[G0 * 4 + 2], X[G0 * 4 + 3]);
  unsigned b1 = cvtpk(X[G0 * 4 + 6], X[G0 * 4 + 7]);
  plswap(a1, b1);
  union {
    unsigned w[4];
    bf16x8 v;
  } u;
  u.w[0] = a0;
  u.w[1] = a1;
  u.w[2] = b0;
  u.w[3] = b1;
  return u.v;
}

// ---------------------------------------------------------------------------
// FAST PATH: f32->bf16 convert pass + global_load_lds GEMMs.
// ---------------------------------------------------------------------------
__device__ __forceinline__ void gload16(const bf16* g, bf16* l) {
  __builtin_amdgcn_global_load_lds(
      (const __attribute__((address_space(1))) void*)g,
      (__attribute__((address_space(3))) void*)l, 16, 0, 0);
}

// Convert tensors: y<3 -> X (1M f32), y in 3..5 -> Wq/Wk/Wv (8M), y==6 -> Wfc.
__global__ __launch_bounds__(256)
void cvt7(const float* __restrict__ x0, const float* __restrict__ x1,
          const float* __restrict__ x2, const float* __restrict__ w0,
          const float* __restrict__ w1, const float* __restrict__ w2,
          const float* __restrict__ w3, bf16* __restrict__ xo,
          bf16* __restrict__ wo, bf16* __restrict__ wfo) {
  const int y = blockIdx.y;
  const int i = (blockIdx.x * 256 + threadIdx.x) * 8;
  const float* s;
  bf16* d;
  int n;
  if (y < 3) {
    s = (y == 0) ? x0 : (y == 1) ? x1 : x2;
    d = xo + (size_t)y * 1048576;
    n = 1048576;
  } else if (y < 6) {
    const int z = y - 3;
    s = (z == 0) ? w0 : (z == 1) ? w1 : w2;
    d = wo + (size_t)z * 8388608;
    n = 8388608;
  } else {
    s = w3;
    d = wfo;
    n = 8388608;
  }
  if (i >= n) return;
  f32x4 a = *(const f32x4*)(s + i);
  f32x4 b = *(const f32x4*)(s + i + 4);
  bf16x8 v;
#pragma unroll
  for (int j = 0; j < 4; ++j) {
    v[j] = (bf16)a[j];
    v[j + 4] = (bf16)b[j];
  }
  *(bf16x8*)(d + i) = v;
}

__global__ __launch_bounds__(256)
void cvt1(const float* __restrict__ s, bf16* __restrict__ d, int n) {
  const int i = (blockIdx.x * 256 + threadIdx.x) * 8;
  if (i >= n) return;
  f32x4 a = *(const f32x4*)(s + i);
  f32x4 b = *(const f32x4*)(s + i + 4);
  bf16x8 v;
#pragma unroll
  for (int j = 0; j < 4; ++j) {
    v[j] = (bf16)a[j];
    v[j + 4] = (bf16)b[j];
  }
  *(bf16x8*)(d + i) = v;
}

// ---------------------------------------------------------------------------
// 8-wave deep-phase QKV GEMM (T3+T4+T5, linear LDS per m198).
// 256x256 tile, BK=32, 512 threads (2M x 4N waves, each 128x64 out).
// LDS: 2 dbuf x (256x32) per matrix = 64KB total. 1 block/CU.
// Per K-tile t (parity d=t&1), two phases:
//   A: vmcnt-gated earlier; read B-frags(4)+A-frags fm0-3; issue stageA(t+1)
//      [WAR-safe: As[d^1] last read in B(t-1), barrier-separated]; 16 MFMA.
//   B: read A-frags fm4-7; issue stageB(t+2) [WAR-safe: Bs[d] reads were in
//      A(t), barrier-separated]; 16 MFMA; counted vmcnt gate for tile t+1
//      (2 newest stage-groups stay in flight -> T4); barrier.
// RAW proof: gate leaves only stageB(t+2) pending; A(t+1)@A(t) and
// B(t+1)@B(t-1) drained; barrier after gate publishes block-wide.
// ---------------------------------------------------------------------------
__global__ __launch_bounds__(512, 2)
void qkv_gemm_8ph(const bf16* __restrict__ Xc, const bf16* __restrict__ Wc,
                  const float* __restrict__ Bq, const float* __restrict__ Bk,
                  const float* __restrict__ Bv, bf16* __restrict__ Qo,
                  bf16* __restrict__ Ko, bf16* __restrict__ Vo, float qsc) {
  __shared__ bf16 As[2 * 8192];
  __shared__ bf16 Bs[2 * 8192];
  const int slice = blockIdx.y;
  const bf16* Ap = Xc + (size_t)slice * 1048576;
  const bf16* Bp = Wc + (size_t)slice * 8388608;
  const float* bias = (slice == 0) ? Bq : (slice == 1) ? Bk : Bv;
  const int tm = (blockIdx.x >> 5) << 8;  // 4 m-tiles
  const int tn = (blockIdx.x & 31) << 8;  // 32 n-tiles
  const int tid = threadIdx.x;
  const int w = tid >> 6, l = tid & 63;
  const int l15 = l & 15, quad = l >> 4;
  const int wr = w >> 2, wc = w & 3;

  // stage geometry: panel 256x32, thread covers rows j*128 + w*16 + (l>>2)
  const int srow = w * 16 + (l >> 2);
  const int scol = (l & 3) * 8;

  auto stageA = [&](int t) {
    const int k0 = t << 5;
    bf16* dst = As + (t & 1) * 8192 + w * 512;
#pragma unroll
    for (int j = 0; j < 2; ++j)
      gload16(Ap + (size_t)(tm + j * 128 + srow) * 1024 + k0 + scol,
              dst + j * 4096);
  };
  auto stageB = [&](int t) {
    const int k0 = t << 5;
    bf16* dst = Bs + (t & 1) * 8192 + w * 512;
#pragma unroll
    for (int j = 0; j < 2; ++j)
      gload16(Bp + (size_t)(tn + j * 128 + srow) * 1024 + k0 + scol,
              dst + j * 4096);
  };

  f32x4 acc[8][4] = {};

  // prologue: tile0 (A+B) + B of tile1; gate leaves B1 in flight
  stageA(0);
  stageB(0);
  stageB(1);
  asm volatile("s_waitcnt vmcnt(2)" ::: "memory");
  __builtin_amdgcn_s_barrier();

  for (int t = 0; t < 32; ++t) {
    const int d = (t & 1) * 8192;

    // ---- phase A ----
    bf16x8 bfr[4], af[4];
#pragma unroll
    for (int fn = 0; fn < 4; ++fn)
      bfr[fn] = *(const bf16x8*)(Bs + d + (wc * 64 + fn * 16 + l15) * 32 + quad * 8);
#pragma unroll
    for (int fm = 0; fm < 4; ++fm)
      af[fm] = *(const bf16x8*)(As + d + (wr * 128 + fm * 16 + l15) * 32 + quad * 8);
    if (t + 1 < 32) stageA(t + 1);
    __builtin_amdgcn_s_setprio(1);
#pragma unroll
    for (int fm = 0; fm < 4; ++fm)
#pragma unroll
      for (int fn = 0; fn < 4; ++fn)
        acc[fm][fn] = __builtin_amdgcn_mfma_f32_16x16x32_bf16(af[fm], bfr[fn],
                                                              acc[fm][fn], 0, 0, 0);
    __builtin_amdgcn_s_setprio(0);
    __builtin_amdgcn_s_barrier();  // phase-A reads complete block-wide

    // ---- phase B ----
#pragma unroll
    for (int fm = 0; fm < 4; ++fm)
      af[fm] = *(const bf16x8*)(As + d + (wr * 128 + (fm + 4) * 16 + l15) * 32 + quad * 8);
    if (t + 2 < 32) stageB(t + 2);
    __builtin_amdgcn_s_setprio(1);
#pragma unroll
    for (int fm = 0; fm < 4; ++fm)
#pragma unroll
      for (int fn = 0; fn < 4; ++fn)
        acc[fm + 4][fn] = __builtin_amdgcn_mfma_f32_16x16x32_bf16(af[fm], bfr[fn],
                                                                  acc[fm + 4][fn], 0, 0, 0);
    __builtin_amdgcn_s_setprio(0);

    if (t < 31) {
      // gate for tile t+1; counted (never 0) except before the last tile
      if (t == 30)
        asm volatile("s_waitcnt vmcnt(0)" ::: "memory");
      else
        asm volatile("s_waitcnt vmcnt(2)" ::: "memory");
      __builtin_amdgcn_s_barrier();  // publishes staged data + phase-B reads
    }
  }

  // epilogue scatter (same layouts as 2-phase kernel)
  if (slice == 2) {
#pragma unroll
    for (int fm = 0; fm < 8; ++fm) {
#pragma unroll
      for (int fn = 0; fn < 4; ++fn) {
        const int n = tn + wc * 64 + fn * 16 + l15;
        const int dd = n & 127, h = (n >> 7) & 7, c = n >> 10;
        const float bv = bias[n];
        const int m0 = tm + wr * 128 + fm * 16 + quad * 4;
        const int b = m0 >> 8, s0 = m0 & 255;
        const size_t idx = ((size_t)((b * 8 + h) * 128 + dd)) * 2048 + (c << 8) + s0;
        bf16x4 ov;
#pragma unroll
        for (int r = 0; r < 4; ++r) ov[r] = (bf16)(acc[fm][fn][r] + bv);
        *(bf16x4*)(Vo + idx) = ov;
      }
    }
  } else {
    bf16* O = slice ? Ko : Qo;
    const float osc = slice ? 1.0f : qsc;
#pragma unroll
    for (int fm = 0; fm < 8; ++fm) {
#pragma unroll
      for (int fn = 0; fn < 4; ++fn) {
        const int n = tn + wc * 64 + fn * 16 + l15;
        const int dd = n & 127, h = (n >> 7) & 7, c = n >> 10;
        const float bv = bias[n];
#pragma unroll
        for (int r = 0; r < 4; ++r) {
          const int m = tm + wr * 128 + fm * 16 + quad * 4 + r;
          const int b = m >> 8, s = m & 255;
          const int row = slice ? ((c << 8) | s) : ((s << 3) | c);
          const size_t idx = ((size_t)(b * 8 + h) * 2048 + row) * 128 + dd;
          O[idx] = (bf16)((acc[fm][fn][r] + bv) * osc);
        }
      }
    }
  }
}

// Pipelined K-loop (2-phase, verified): NT GEMM 128x128 tile, BK=32.
__device__ __forceinline__ void gemm_core_pipe(const bf16* __restrict__ A,
                                               const bf16* __restrict__ B,
                                               bf16* As, bf16* Bs, int K,
                                               int kbeg, int kend, int tm,
                                               int tn, f32x4 (&acc)[4][4]) {
  const int tid = threadIdx.x;
  const int w = tid >> 6, l = tid & 63;
  const int l15 = l & 15, quad = l >> 4;
  const int wm = (w >> 1) << 6, wn = (w & 1) << 6;
  const int rsub = l >> 2, csub = (l & 3) * 8;
  const int nt = (kend - kbeg) >> 5;

  auto stage = [&](int t) {
    const int k0 = kbeg + (t << 5);
    const int buf = (t & 1) * 4096;
#pragma unroll
    for (int c2 = 0; c2 < 2; ++c2) {
      const int c = w * 2 + c2;
      gload16(A + (size_t)(tm + c * 16 + rsub) * K + k0 + csub,
              As + buf + c * 512);
      gload16(B + (size_t)(tn + c * 16 + rsub) * K + k0 + csub,
              Bs + buf + c * 512);
    }
  };

  stage(0);

  for (int t = 0; t < nt; ++t) {
    __syncthreads();
    if (t + 1 < nt) stage(t + 1);

    const int buf = (t & 1) * 4096;
    bf16x8 af[4], bfr[4];
#pragma unroll
    for (int i = 0; i < 4; ++i)
      af[i] = *(const bf16x8*)(As + buf + (wm + i * 16 + l15) * 32 + quad * 8);
#pragma unroll
    for (int j = 0; j < 4; ++j)
      bfr[j] = *(const bf16x8*)(Bs + buf + (wn + j * 16 + l15) * 32 + quad * 8);
#pragma unroll
    for (int i = 0; i < 4; ++i)
#pragma unroll
      for (int j = 0; j < 4; ++j)
        acc[i][j] = __builtin_amdgcn_mfma_f32_16x16x32_bf16(af[i], bfr[j],
                                                            acc[i][j], 0, 0, 0);
  }
}

// 2-phase fused QKV (120MB path), verified.
__global__ __launch_bounds__(256, 4)
void qkv_gemm_lds(const bf16* __restrict__ Xc, const bf16* __restrict__ Wc,
                  const float* __restrict__ Bq, const float* __restrict__ Bk,
                  const float* __restrict__ Bv, bf16* __restrict__ Qo,
                  bf16* __restrict__ Ko, bf16* __restrict__ Vo, float qsc) {
  __shared__ bf16 As[2 * 4096];
  __shared__ bf16 Bs[2 * 4096];
  const int slice = blockIdx.y;
  const bf16* A = Xc + (size_t)slice * 1048576;
  const bf16* B = Wc + (size_t)slice * 8388608;
  const float* bias = (slice == 0) ? Bq : (slice == 1) ? Bk : Bv;
  const int tm = (blockIdx.x >> 6) << 7;
  const int tn = (blockIdx.x & 63) << 7;

  f32x4 acc[4][4] = {};
  gemm_core_pipe(A, B, As, Bs, 1024, 0, 1024, tm, tn, acc);

  const int tid = threadIdx.x;
  const int w = tid >> 6, l = tid & 63;
  const int l15 = l & 15, quad = l >> 4;
  const int wm = (w >> 1) << 6, wn = (w & 1) << 6;

  if (slice == 2) {
#pragma unroll
    for (int i = 0; i < 4; ++i) {
#pragma unroll
      for (int j = 0; j < 4; ++j) {
        const int n = tn + wn + j * 16 + l15;
        const int d = n & 127, h = (n >> 7) & 7, c = n >> 10;
        const float bv = bias[n];
        const int m0 = tm + wm + i * 16 + quad * 4;
        const int b = m0 >> 8, s0 = m0 & 255;
        const size_t idx = ((size_t)((b * 8 + h) * 128 + d)) * 2048 + (c << 8) + s0;
        bf16x4 ov;
#pragma unroll
        for (int r = 0; r < 4; ++r) ov[r] = (bf16)(acc[i][j][r] + bv);
        *(bf16x4*)(Vo + idx) = ov;
      }
    }
  } else {
    bf16* O = slice ? Ko : Qo;
    const float osc = slice ? 1.0f : qsc;
#pragma unroll
    for (int i = 0; i < 4; ++i) {
#pragma unroll
      for (int j = 0; j < 4; ++j) {
        const int n = tn + wn + j * 16 + l15;
        const int d = n & 127, h = (n >> 7) & 7, c = n >> 10;
        const float bv = bias[n];
#pragma unroll
        for (int r = 0; r < 4; ++r) {
          const int m = tm + wm + i * 16 + quad * 4 + r;
          const int b = m >> 8, s = m & 255;
          const int row = slice ? ((c << 8) | s) : ((s << 3) | c);
          const size_t idx = ((size_t)(b * 8 + h) * 2048 + row) * 128 + d;
          O[idx] = (bf16)((acc[i][j][r] + bv) * osc);
        }
      }
    }
  }
}

// Output projection, split-K x8 (verified 2-phase).
__global__ __launch_bounds__(256, 4)
void fc_gemm_lds(const bf16* __restrict__ A, const bf16* __restrict__ B,
                 float* __restrict__ C) {
  __shared__ bf16 As[2 * 4096];
  __shared__ bf16 Bs[2 * 4096];
  const int tm = (blockIdx.x >> 3) << 7;
  const int tn = (blockIdx.x & 7) << 7;
  const int kbeg = blockIdx.y << 10;

  f32x4 acc[4][4] = {};
  gemm_core_pipe(A, B, As, Bs, 8192, kbeg, kbeg + 1024, tm, tn, acc);

  const int tid = threadIdx.x;
  const int w = tid >> 6, l = tid & 63;
  const int l15 = l & 15, quad = l >> 4;
  const int wm = (w >> 1) << 6, wn = (w & 1) << 6;
  const size_t koff = (size_t)blockIdx.y * 1048576;
#pragma unroll
  for (int i = 0; i < 4; ++i) {
#pragma unroll
    for (int j = 0; j < 4; ++j) {
      const int n = tn + wn + j * 16 + l15;
#pragma unroll
      for (int r = 0; r < 4; ++r) {
        const int m = tm + wm + i * 16 + quad * 4 + r;
        C[koff + (size_t)m * 1024 + n] = acc[i][j][r];
      }
    }
  }
}

// Sum 8 split-K partials + bias -> f32 out.
__global__ __launch_bounds__(256)
void splitk_reduce(const float* __restrict__ P, const float* __restrict__ bias,
                   float* __restrict__ out) {
  const int i = (blockIdx.x * 256 + threadIdx.x) * 4;
  const int n = i & 1023;
  f32x4 s = *(const f32x4*)(bias + n);
#pragma unroll
  for (int kc = 0; kc < 8; ++kc)
    s += *(const f32x4*)(P + (size_t)kc * 1048576 + i);
  *(f32x4*)(out + i) = s;
}

// ---------------------------------------------------------------------------
// Flash attention (round-6 verified): full-KV, double-buffered 64KB LDS,
// one barrier per tile, v_max3 tree + defer-max + VALU row-sum.
// ---------------------------------------------------------------------------
__global__ __launch_bounds__(256, 2)
void attn_kernel(const bf16* __restrict__ Q, const bf16* __restrict__ Kc,
                 const bf16* __restrict__ Vt, bf16* __restrict__ O2) {
  __shared__ bf16x8 KsV[2048];
  __shared__ bf16x8 VsV[2048];
  char* KsB = (char*)KsV;
  char* VsB = (char*)VsV;

  const int tid = threadIdx.x;
  const int w = tid >> 6, l = tid & 63;
  const int l31 = l & 31, hi = l >> 5;
  const int wg = ((blockIdx.x & 7) << 6) | (blockIdx.x >> 3);
  const int bh = wg >> 4;
  const int qc = wg & 15;
  const int b = bh >> 3, h = bh & 7;
  const int q0w = qc * 128 + w * 32;
  const size_t qkbase = (size_t)bh * 2048 * 128;
  const size_t vbase = (size_t)bh * 128 * 2048;

  bf16x8 qf[8];
#pragma unroll
  for (int dc = 0; dc < 8; ++dc)
    qf[dc] = *(const bf16x8*)(Q + qkbase + (size_t)(q0w + l31) * 128 + dc * 16 + hi * 8);

  f32x16 oacc[4] = {};
  float m = -1e30f, lsum = 0.f;

  bf16x8 kreg[4], vreg[4];
  auto stage_load = [&](int kk) {
#pragma unroll
    for (int pc = 0; pc < 4; ++pc) {
      const int c = tid + pc * 256;
      kreg[pc] = *(const bf16x8*)(Kc + qkbase + (size_t)(kk + (c >> 4)) * 128 + (c & 15) * 8);
      vreg[pc] = *(const bf16x8*)(Vt + vbase + (size_t)(c >> 3) * 2048 + kk + (c & 7) * 8);
    }
  };
  auto stage_write = [&](int buf) {
    const int off = buf << 14;
#pragma unroll
    for (int pc = 0; pc < 4; ++pc) {
      const int c = tid + pc * 256;
      const int kr = c >> 4, kcol = c & 15;
      *(bf16x8*)(KsB + off + ((kr * 256 + kcol * 16) ^ ((kr & 15) << 4))) = kreg[pc];
      const int vr = c >> 3, vcol = c & 7;
      *(bf16x8*)(VsB + off + ((vr * 128 + vcol * 16) ^ ((vr & 7) << 4))) = vreg[pc];
    }
  };

  stage_load(0);
  stage_write(0);
  __syncthreads();
  int cur = 0;

  for (int it = 0; it < 32; ++it) {
    if (it < 31) stage_load((it + 1) * 64);
    const int koff = cur << 14;

    f32x16 sa = {}, sb = {};
    __builtin_amdgcn_s_setprio(1);
#pragma unroll
    for (int dc = 0; dc < 8; ++dc) {
      const int colb = dc * 32 + hi * 16;
      bf16x8 ka = *(const bf16x8*)(KsB + koff + ((l31 * 256 + colb) ^ ((l31 & 15) << 4)));
      bf16x8 kb = *(const bf16x8*)(KsB + koff + (((32 + l31) * 256 + colb) ^ ((l31 & 15) << 4)));
      sa = __builtin_amdgcn_mfma_f32_32x32x16_bf16(ka, qf[dc], sa, 0, 0, 0);
      sb = __builtin_amdgcn_mfma_f32_32x32x16_bf16(kb, qf[dc], sb, 0, 0, 0);
    }
    __builtin_amdgcn_s_setprio(0);

    float mt;
    {
      float p0 = f3(sa[0], sa[1], sa[2]);
      float p1 = f3(sa[3], sa[4], sa[5]);
      float p2 = f3(sa[6], sa[7], sa[8]);
      float p3 = f3(sa[9], sa[10], sa[11]);
      float p4 = f3(sa[12], sa[13], sa[14]);
      float q0 = f3(sb[0], sb[1], sb[2]);
      float q1 = f3(sb[3], sb[4], sb[5]);
      float q2 = f3(sb[6], sb[7], sb[8]);
      float q3 = f3(sb[9], sb[10], sb[11]);
      float q4 = f3(sb[12], sb[13], sb[14]);
      float u0 = f3(p0, p1, p2);
      float u1 = f3(p3, p4, sa[15]);
      float u2 = f3(q0, q1, q2);
      float u3 = f3(q3, q4, sb[15]);
      mt = fmaxf(fmaxf(u0, u1), fmaxf(u2, u3));
      mt = xhalf_max(mt);
    }
    if (!__all(mt - m <= 8.0f)) {  // defer-max (T13)
      const float mn = fmaxf(m, mt);
      const float al = __builtin_amdgcn_exp2f(m - mn);
      m = mn;
      lsum *= al;
#pragma unroll
      for (int dt = 0; dt < 4; ++dt)
#pragma unroll
        for (int i = 0; i < 16; ++i) oacc[dt][i] *= al;
    }
#pragma unroll
    for (int i = 0; i < 16; ++i) sa[i] = __builtin_amdgcn_exp2f(sa[i] - m);
#pragma unroll
    for (int i = 0; i < 16; ++i) sb[i] = __builtin_amdgcn_exp2f(sb[i] - m);
    float r0 = 0.f, r1 = 0.f, r2 = 0.f, r3 = 0.f;
#pragma unroll
    for (int i = 0; i < 4; ++i) {
      r0 += sa[i]; r1 += sa[4 + i]; r2 += sa[8 + i]; r3 += sa[12 + i];
    }
#pragma unroll
    for (int i = 0; i < 4; ++i) {
      r0 += sb[i]; r1 += sb[4 + i]; r2 += sb[8 + i]; r3 += sb[12 + i];
    }
    lsum += xhalf_sum((r0 + r1) + (r2 + r3));

    bf16x8 pf[4];
    pf[0] = build_pfrag<0>(sa);
    pf[1] = build_pfrag<2>(sa);
    pf[2] = build_pfrag<0>(sb);
    pf[3] = build_pfrag<2>(sb);

    __builtin_amdgcn_s_setprio(1);
#pragma unroll
    for (int dt = 0; dt < 4; ++dt) {
      const int d = dt * 32 + l31;
#pragma unroll
      for (int c = 0; c < 4; ++c) {
        bf16x8 vf = *(const bf16x8*)(VsB + koff + ((d * 128 + c * 32 + hi * 16) ^ ((d & 7) << 4)));
        oacc[dt] = __builtin_amdgcn_mfma_f32_32x32x16_bf16(vf, pf[c], oacc[dt], 0, 0, 0);
      }
    }
    __builtin_amdgcn_s_setprio(0);

    if (it < 31) stage_write(cur ^ 1);
    __syncthreads();
    cur ^= 1;
  }

  const float inv = 1.0f / lsum;
  const int t = q0w + l31;
  const size_t obase = (size_t)(b * 256 + (t >> 3)) * 8192 + (t & 7) * 1024 + h * 128;
#pragma unroll
  for (int dt = 0; dt < 4; ++dt) {
#pragma unroll
    for (int g = 0; g < 4; ++g) {
      const int d = dt * 32 + 8 * g + 4 * hi;
      bf16x4 ov;
#pragma unroll
      for (int r = 0; r < 4; ++r) ov[r] = (bf16)(oacc[dt][g * 4 + r] * inv);
      *(bf16x4*)(O2 + obase + d) = ov;
    }
  }
}

// ---------------------------------------------------------------------------
// FALLBACK GEMMs (ws < 120MB), verified earlier.
// ---------------------------------------------------------------------------
__global__ __launch_bounds__(256, 4)
void qkv_proj(const float* __restrict__ Xq, const float* __restrict__ Xk,
              const float* __restrict__ Xv, const float* __restrict__ Wq,
              const float* __restrict__ Wk, const float* __restrict__ Wv,
              const float* __restrict__ Bq, const float* __restrict__ Bk,
              const float* __restrict__ Bv, bf16* __restrict__ Qo,
              bf16* __restrict__ Ko, bf16* __restrict__ Vo, float qsc) {
  __shared__ bf16 As[128 * SLD];
  __shared__ bf16 Bs[128 * SLD];
  const int slice = blockIdx.y;
  const float* A = (slice == 0) ? Xq : (slice == 1) ? Xk : Xv;
  const float* W = (slice == 0) ? Wq : (slice == 1) ? Wk : Wv;
  const float* bias = (slice == 0) ? Bq : (slice == 1) ? Bk : Bv;

  const int tid = threadIdx.x;
  const int w = tid >> 6, l = tid & 63;
  const int l15 = l & 15, quad = l >> 4;
  const int tm = (blockIdx.x >> 6) << 7;
  const int tn = (blockIdx.x & 63) << 7;
  const int wm = (w >> 1) << 6;
  const int wn = (w & 1) << 6;

  const int frow = tid >> 1;
  const int fch = (tid & 1) * 16;

  f32x4 acc[4][4] = {};
  f32x4 ar[4], br[4];

  auto load_regs = [&](int k0) {
    const float* sA = A + (size_t)(tm + frow) * 1024 + k0 + fch;
    ar[0] = *(const f32x4*)(sA);
    ar[1] = *(const f32x4*)(sA + 4);
    ar[2] = *(const f32x4*)(sA + 8);
    ar[3] = *(const f32x4*)(sA + 12);
    const float* sB = W + (size_t)(tn + frow) * 1024 + k0 + fch;
    br[0] = *(const f32x4*)(sB);
    br[1] = *(const f32x4*)(sB + 4);
    br[2] = *(const f32x4*)(sB + 8);
    br[3] = *(const f32x4*)(sB + 12);
  };
  auto write_lds = [&]() {
    bf16x8 y0, y1;
#pragma unroll
    for (int j = 0; j < 4; ++j) {
      y0[j] = (bf16)ar[0][j]; y0[j + 4] = (bf16)ar[1][j];
      y1[j] = (bf16)ar[2][j]; y1[j + 4] = (bf16)ar[3][j];
    }
    *(bf16x8*)(As + frow * SLD + fch) = y0;
    *(bf16x8*)(As + frow * SLD + fch + 8) = y1;
#pragma unroll
    for (int j = 0; j < 4; ++j) {
      y0[j] = (bf16)br[0][j]; y0[j + 4] = (bf16)br[1][j];
      y1[j] = (bf16)br[2][j]; y1[j + 4] = (bf16)br[3][j];
    }
    *(bf16x8*)(Bs + frow * SLD + fch) = y0;
    *(bf16x8*)(Bs + frow * SLD + fch + 8) = y1;
  };

  load_regs(0);
  write_lds();
  __syncthreads();

  for (int k0 = 0; k0 < 1024; k0 += 32) {
    const bool more = (k0 + 32) < 1024;
    if (more) load_regs(k0 + 32);

    bf16x8 af[4], bfr[4];
#pragma unroll
    for (int i = 0; i < 4; ++i)
      af[i] = *(const bf16x8*)(As + (wm + i * 16 + l15) * SLD + quad * 8);
#pragma unroll
    for (int j = 0; j < 4; ++j)
      bfr[j] = *(const bf16x8*)(Bs + (wn + j * 16 + l15) * SLD + quad * 8);
#pragma unroll
    for (int i = 0; i < 4; ++i)
#pragma unroll
      for (int j = 0; j < 4; ++j)
        acc[i][j] = __builtin_amdgcn_mfma_f32_16x16x32_bf16(af[i], bfr[j], acc[i][j], 0, 0, 0);

    __syncthreads();
    if (more) {
      write_lds();
      __syncthreads();
    }
  }

  if (slice == 2) {
#pragma unroll
    for (int i = 0; i < 4; ++i) {
#pragma unroll
      for (int j = 0; j < 4; ++j) {
        const int n = tn + wn + j * 16 + l15;
        const int d = n & 127, h = (n >> 7) & 7, c = n >> 10;
        const float bv = bias[n];
        const int m0 = tm + wm + i * 16 + quad * 4;
        const int b = m0 >> 8, s0 = m0 & 255;
        const size_t idx = ((size_t)((b * 8 + h) * 128 + d)) * 2048 + (c << 8) + s0;
        bf16x4 ov;
#pragma unroll
        for (int r = 0; r < 4; ++r) ov[r] = (bf16)(acc[i][j][r] + bv);
        *(bf16x4*)(Vo + idx) = ov;
      }
    }
  } else {
    bf16* O = slice ? Ko : Qo;
    const float osc = slice ? 1.0f : qsc;
#pragma unroll
    for (int i = 0; i < 4; ++i) {
#pragma unroll
      for (int j = 0; j < 4; ++j) {
        const int n = tn + wn + j * 16 + l15;
        const int d = n & 127, h = (n >> 7) & 7, c = n >> 10;
        const float bv = bias[n];
#pragma unroll
        for (int r = 0; r < 4; ++r) {
          const int m = tm + wm + i * 16 + quad * 4 + r;
          const int b = m >> 8, s = m & 255;
          const int row = slice ? ((c << 8) | s) : ((s << 3) | c);
          const size_t idx = ((size_t)(b * 8 + h) * 2048 + row) * 128 + d;
          O[idx] = (bf16)((acc[i][j][r] + bv) * osc);
        }
      }
    }
  }
}

__global__ __launch_bounds__(256, 4)
void gemm_fc_f32(const bf16* __restrict__ Ap, const float* __restrict__ Bp,
                 float* __restrict__ C) {
  __shared__ bf16 As[128 * SLD];
  __shared__ bf16 Bs[128 * SLD];
  const int tid = threadIdx.x;
  const int w = tid >> 6, l = tid & 63;
  const int l15 = l & 15, quad = l >> 4;
  const int tm = (blockIdx.x >> 3) << 7;
  const int tn = (blockIdx.x & 7) << 7;
  const int wm = (w >> 1) << 6;
  const int wn = (w & 1) << 6;
  const int K = 8192;

  f32x4 acc[4][4] = {};
  const int frow = tid >> 1;
  const int fch = (tid & 1) * 16;
  const int kbeg = blockIdx.y << 10;
  const int kend = kbeg + 1024;

  f32x4 brf[4];
  bf16x8 arb[2];

  auto load_regs = [&](int k0) {
#pragma unroll
    for (int pc = 0; pc < 2; ++pc) {
      const int c = tid + pc * 256;
      const int r = c >> 2, col = (c & 3) * 8;
      arb[pc] = *(const bf16x8*)(Ap + (size_t)(tm + r) * K + k0 + col);
    }
    const float* src = Bp + (size_t)(tn + frow) * K + k0 + fch;
    brf[0] = *(const f32x4*)(src);
    brf[1] = *(const f32x4*)(src + 4);
    brf[2] = *(const f32x4*)(src + 8);
    brf[3] = *(const f32x4*)(src + 12);
  };
  auto write_lds = [&]() {
#pragma unroll
    for (int pc = 0; pc < 2; ++pc) {
      const int c = tid + pc * 256;
      const int r = c >> 2, col = (c & 3) * 8;
      *(bf16x8*)(As + r * SLD + col) = arb[pc];
    }
    bf16x8 y0, y1;
#pragma unroll
    for (int j = 0; j < 4; ++j) {
      y0[j] = (bf16)brf[0][j]; y0[j + 4] = (bf16)brf[1][j];
      y1[j] = (bf16)brf[2][j]; y1[j + 4] = (bf16)brf[3][j];
    }
    *(bf16x8*)(Bs + frow * SLD + fch) = y0;
    *(bf16x8*)(Bs + frow * SLD + fch + 8) = y1;
  };

  load_regs(kbeg);
  write_lds();
  __syncthreads();

  for (int k0 = kbeg; k0 < kend; k0 += 32) {
    const bool more = (k0 + 32) < kend;
    if (more) load_regs(k0 + 32);

    bf16x8 af[4], bfr[4];
#pragma unroll
    for (int i = 0; i < 4; ++i)
      af[i] = *(const bf16x8*)(As + (wm + i * 16 + l15) * SLD + quad * 8);
#pragma unroll
    for (int j = 0; j < 4; ++j)
      bfr[j] = *(const bf16x8*)(Bs + (wn + j * 16 + l15) * SLD + quad * 8);
#pragma unroll
    for (int i = 0; i < 4; ++i)
#pragma unroll
      for (int j = 0; j < 4; ++j)
        acc[i][j] = __builtin_amdgcn_mfma_f32_16x16x32_bf16(af[i], bfr[j], acc[i][j], 0, 0, 0);

    __syncthreads();
    if (more) {
      write_lds();
      __syncthreads();
    }
  }

  const size_t koff = (size_t)blockIdx.y * 1048576;
#pragma unroll
  for (int i = 0; i < 4; ++i) {
#pragma unroll
    for (int j = 0; j < 4; ++j) {
      const int n = tn + wn + j * 16 + l15;
#pragma unroll
      for (int r = 0; r < 4; ++r) {
        const int m = tm + wm + i * 16 + quad * 4 + r;
        C[koff + (size_t)m * 1024 + n] = acc[i][j][r];
      }
    }
  }
}

extern "C" void kernel_launch(void* const* d_in, const int* in_sizes, int n_in,
                              void* d_out, int out_size, void* d_ws, size_t ws_size,
                              hipStream_t stream) {
  const float* query = (const float*)d_in[0];
  const float* key_ = (const float*)d_in[1];
  const float* value = (const float*)d_in[2];
  const float* Wq = (const float*)d_in[3];
  const float* bq = (const float*)d_in[4];
  const float* Wk = (const float*)d_in[5];
  const float* bk = (const float*)d_in[6];
  const float* Wv = (const float*)d_in[7];
  const float* bv = (const float*)d_in[8];
  const float* Wfc = (const float*)d_in[9];
  const float* bfc = (const float*)d_in[10];
  float* out = (float*)d_out;  // output dtype FLOAT32

  const size_t MB = 1024 * 1024;
  bf16* Qws = (bf16*)d_ws;          // [0,16MB)
  bf16* Kws = Qws + 8 * MB;         // [16,32)
  bf16* Vtw = Kws + 8 * MB;         // [32,48)
  bf16* O2 = Vtw + 8 * MB;          // [48,64)
  float* Pk = (float*)((char*)d_ws + 16 * MB);  // [16,48) after attn

  const float QSC = 1.4426950408889634f / 32.0f;  // log2e / sqrt(HID)
  dim3 blk(256);

  if (ws_size >= (size_t)136 * MB) {
    // FAST PATH: convert all 7 tensors; 8-phase QKV; full-KV attn; split-K fc.
    bf16* Xc = (bf16*)((char*)d_ws + 64 * MB);    // [64,70)
    bf16* Wc = (bf16*)((char*)d_ws + 70 * MB);    // [70,118)
    bf16* Wfcc = (bf16*)((char*)d_ws + 118 * MB); // [118,134)

    cvt7<<<dim3(4096, 7), blk, 0, stream>>>(query, key_, value, Wq, Wk, Wv,
                                            Wfc, Xc, Wc, Wfcc);
    qkv_gemm_8ph<<<dim3(128, 3), dim3(512), 0, stream>>>(Xc, Wc, bq, bk, bv,
                                                         Qws, Kws, Vtw, QSC);
    attn_kernel<<<512, blk, 0, stream>>>(Qws, Kws, Vtw, O2);
    fc_gemm_lds<<<dim3(64, 8), blk, 0, stream>>>(O2, Wfcc, Pk);
    splitk_reduce<<<1024, blk, 0, stream>>>(Pk, bfc, out);
  } else if (ws_size >= (size_t)120 * MB) {
    // FAST PATH, 2-phase qkv; Wfc converted after attn into dead Q region.
    bf16* Xc = (bf16*)((char*)d_ws + 64 * MB);
    bf16* Wc = (bf16*)((char*)d_ws + 70 * MB);
    bf16* Wfcc = Qws;  // reuse Qws after attn

    cvt7<<<dim3(4096, 6), blk, 0, stream>>>(query, key_, value, Wq, Wk, Wv,
                                            Wfc, Xc, Wc, nullptr);
    qkv_gemm_lds<<<dim3(512, 3), blk, 0, stream>>>(Xc, Wc, bq, bk, bv, Qws, Kws, Vtw, QSC);
    attn_kernel<<<512, blk, 0, stream>>>(Qws, Kws, Vtw, O2);
    cvt1<<<4096, blk, 0, stream>>>(Wfc, Wfcc, 8388608);
    fc_gemm_lds<<<dim3(64, 8), blk, 0, stream>>>(O2, Wfcc, Pk);
    splitk_reduce<<<1024, blk, 0, stream>>>(Pk, bfc, out);
  } else {
    // FALLBACK (fits in 64MB ws).
    qkv_proj<<<dim3(512, 3), blk, 0, stream>>>(query, key_, value, Wq, Wk, Wv,
                                               bq, bk, bv, Qws, Kws, Vtw, QSC);
    attn_kernel<<<512, blk, 0, stream>>>(Qws, Kws, Vtw, O2);
    gemm_fc_f32<<<dim3(64, 8), blk, 0, stream>>>(O2, Wfc, Pk);
    splitk_reduce<<<1024, blk, 0, stream>>>(Pk, bfc, out);
  }
}